// Round 1
// baseline (652.280 us; speedup 1.0000x reference)
//
#include <hip/hip_runtime.h>

#define HW 9216
#define NPX 36864

// ---------- weight pre-transposes ----------
__global__ __launch_bounds__(256) void prep_weights(
    const float* __restrict__ rw, const float* __restrict__ vw0,
    const float* __restrict__ vw1, const float* __restrict__ vw2,
    const float* __restrict__ fw,
    float* __restrict__ rwT, float* __restrict__ vwT, float* __restrict__ fwT)
{
    int idx = blockIdx.x * 256 + threadIdx.x;
    if (idx < 8192) {                       // reduce_w (64,128) -> rwT[i][c]
        int c = idx & 63, i = idx >> 6;
        rwT[idx] = rw[c * 128 + i];
    } else if (idx < 20480) {               // v_w[lvl] (64,64) -> vwT[lvl][i][c]
        int e = idx - 8192;
        int lvl = e >> 12, r = e & 4095;
        int c = r & 63, i = r >> 6;
        const float* vw = (lvl == 0) ? vw0 : ((lvl == 1) ? vw1 : vw2);
        vwT[e] = vw[c * 64 + i];
    } else if (idx < 167936) {              // fusion_w (64,256,3,3) -> fwT[tap][ci4][co][cj]
        int e = idx - 20480;
        int cj = e & 3, co = (e >> 2) & 63, ci4 = (e >> 8) & 63, tap = e >> 14;
        fwT[e] = fw[co * 2304 + (ci4 * 4 + cj) * 9 + tap];
    }
}

// ---------- transpose key->qT (NHWC) and sup->fused[ch 0:64] ----------
__global__ void pack_kernel(const float* __restrict__ key, const float* __restrict__ sup,
                            float* __restrict__ qT, float* __restrict__ fused)
{
    __shared__ float lk[32][33], ls[32][33];
    int tx = threadIdx.x, ty = threadIdx.y;
    int x0 = blockIdx.x * 32, c0 = blockIdx.y * 32;
    int z = blockIdx.z; int b = z / 96, y = z - b * 96;
    #pragma unroll
    for (int i = 0; i < 32; i += 8) {
        int c = c0 + ty + i;
        lk[ty + i][tx] = key[((b * 64 + c) * 96 + y) * 96 + x0 + tx];
        ls[ty + i][tx] = sup[((b * 64 + c) * 96 + y) * 96 + x0 + tx];
    }
    __syncthreads();
    #pragma unroll
    for (int i = 0; i < 32; i += 8) {
        int px = (b * 96 + y) * 96 + x0 + ty + i;
        qT[px * 64 + c0 + tx]     = lk[tx][ty + i];
        fused[px * 256 + c0 + tx] = ls[tx][ty + i];
    }
}

// ---------- shifted grouped 3x3 conv (shift folded into index math) ----------
__global__ __launch_bounds__(256) void shift_smooth(const float* __restrict__ sup,
    const float* __restrict__ w, const float* __restrict__ bias, float* __restrict__ smooth)
{
    int idx = blockIdx.x * 256 + threadIdx.x;        // < 2359296
    int x = idx % 96; int t1 = idx / 96; int y = t1 % 96; int t2 = t1 / 96;
    int c = t2 & 63; int b = t2 >> 6;
    int g = c >> 3;
    int sh = 3 * ((g >= 5) - (g < 3));
    int m = (g < 3) ? g : ((g < 5) ? ((g == 3) ? 0 : 2) : (g - 5));
    int sw = 3 * m - 3;

    float acc = bias[c];
    const float* wp = w + c * 72;
    for (int ic = 0; ic < 8; ic++) {
        const float* sp = sup + ((b * 64 + g * 8 + ic) * 96) * 96;
        #pragma unroll
        for (int ky = 0; ky < 3; ky++)
            #pragma unroll
            for (int kx = 0; kx < 3; kx++) {
                int yy = y + ky - 1, xx = x + kx - 1;
                int ys = yy - sh, xs = xx - sw;
                float v = 0.f;
                if (yy >= 0 && yy < 96 && xx >= 0 && xx < 96 &&
                    ys >= 0 && ys < 96 && xs >= 0 && xs < 96)
                    v = sp[ys * 96 + xs];
                acc += wp[ic * 9 + ky * 3 + kx] * v;
            }
    }
    smooth[idx] = acc;
}

// ---------- 1x1 reduce conv (128->64), writes sup2 in NHWC ----------
__global__ __launch_bounds__(256) void reduce_kernel(const float* __restrict__ sup,
    const float* __restrict__ smooth, const float* __restrict__ rwT,
    const float* __restrict__ rb, float* __restrict__ sup2)
{
    int gid = blockIdx.x * 256 + threadIdx.x;
    int c = gid & 63, px = gid >> 6;
    int b = px / HW; int rem = px - b * HW;
    const float* s1 = sup + b * 64 * HW + rem;
    const float* s2 = smooth + b * 64 * HW + rem;
    float acc = rb[c];
    for (int i = 0; i < 64; i++) {
        acc += rwT[i * 64 + c] * s1[i * HW];
        acc += rwT[(64 + i) * 64 + c] * s2[i * HW];
    }
    sup2[px * 64 + c] = acc;
}

// ---------- neighborhood attention (one wave per pixel); v-conv folded in ----------
template<int KS>
__global__ __launch_bounds__(64) void natten_kernel(
    const float* __restrict__ qT, const float* __restrict__ k,   // k = sup2 (NHWC)
    const float* __restrict__ vwT, const float* __restrict__ vb,
    const float* __restrict__ rpb, float* __restrict__ fused, int lvl)
{
    constexpr int R = KS / 2, KK = KS * KS, NB = 2 * KS - 1;
    constexpr int NSET = (KK + 7) / 8;
    int lane = threadIdx.x;
    int px = blockIdx.x;
    int b = px / HW; int rem = px - b * HW;
    int y = rem / 96, x = rem - (rem / 96) * 96;
    int ni = y - R; if (ni < 0) ni = 0; if (ni > 96 - KS) ni = 96 - KS;
    int nj = x - R; if (nj < 0) nj = 0; if (nj > 96 - KS) nj = 96 - KS;
    int pi = KS - 1 + ni - y, pj = KS - 1 + nj - x;

    __shared__ __align__(16) float q_lds[64];
    __shared__ float s_lds[64], s2_lds[64];
    q_lds[lane] = qT[px * 64 + lane];
    __syncthreads();

    int cg = lane >> 3, pq = lane & 7;
    float4 qa = *(const float4*)&q_lds[cg * 8];
    float4 qb = *(const float4*)&q_lds[cg * 8 + 4];
    const float* kbase = k + b * HW * 64;

    // scores: lanes split 8 channel-groups x 8 neighbor-columns
    for (int s = 0; s < NSET; s++) {
        int p = s * 8 + pq;
        float partial = 0.f;
        int ky = 0, kx = 0;
        bool act = (p < KK);
        if (act) {
            ky = p / KS; kx = p - ky * KS;
            const float* kp = kbase + ((ni + ky) * 96 + nj + kx) * 64 + cg * 8;
            float4 ka = *(const float4*)kp;
            float4 kb2 = *(const float4*)(kp + 4);
            partial = qa.x * ka.x + qa.y * ka.y + qa.z * ka.z + qa.w * ka.w
                    + qb.x * kb2.x + qb.y * kb2.y + qb.z * kb2.z + qb.w * kb2.w;
        }
        partial += __shfl_xor(partial, 8);
        partial += __shfl_xor(partial, 16);
        partial += __shfl_xor(partial, 32);
        if (act && cg == 0)
            s_lds[p] = partial + rpb[(pi + ky) * NB + pj + kx];
    }
    __syncthreads();

    // softmax across KK entries (single wave)
    float val = (lane < KK) ? s_lds[lane] : -1e30f;
    float mx = val;
    #pragma unroll
    for (int off = 32; off; off >>= 1) mx = fmaxf(mx, __shfl_xor(mx, off));
    float e = (lane < KK) ? __expf(val - mx) : 0.f;
    float ss = e;
    #pragma unroll
    for (int off = 32; off; off >>= 1) ss += __shfl_xor(ss, off);
    if (lane < KK) s_lds[lane] = e / ss;
    __syncthreads();

    // aggregate sup2 with attn weights (v-conv commutes past softmax: sum(attn)=1)
    float sacc = 0.f;
    #pragma unroll
    for (int p = 0; p < KK; p++) {
        int ky = p / KS, kx = p - (p / KS) * KS;
        sacc += s_lds[p] * kbase[((ni + ky) * 96 + nj + kx) * 64 + lane];
    }
    s2_lds[lane] = sacc;
    __syncthreads();

    // apply v projection: out[c] = vb[c] + sum_i vwT[i][c] * sacc[i]
    float outv = vb[lane];
    for (int i = 0; i < 64; i++)
        outv += vwT[i * 64 + lane] * s2_lds[i];
    fused[px * 256 + (lvl + 1) * 64 + lane] = outv;
}

// ---------- 3x3 fusion conv (256->64) + bias + relu ----------
__global__ __launch_bounds__(256) void fusion_kernel(const float* __restrict__ fused,
    const float* __restrict__ fwT, const float* __restrict__ fb, float* __restrict__ out)
{
    __shared__ __align__(16) float lds[6528];   // 3 rows x 34 cols x 64 ci (one chunk)
    int t = threadIdx.x;
    int x0 = blockIdx.x * 32, y = blockIdx.y, b = blockIdx.z;
    int co = t & 63, wv = t >> 6, px0 = wv * 8;
    float acc[8];
    #pragma unroll
    for (int j = 0; j < 8; j++) acc[j] = 0.f;
    const float4* fwT4 = (const float4*)fwT;

    for (int ch = 0; ch < 4; ch++) {
        __syncthreads();
        for (int e = t; e < 6528; e += 256) {
            int ci = e & 63, pos = e >> 6;
            int r = pos / 34, xx = pos - r * 34;
            int yy = y - 1 + r, xc = x0 - 1 + xx;
            float v = 0.f;
            if (yy >= 0 && yy < 96 && xc >= 0 && xc < 96)
                v = fused[(((b * 96 + yy) * 96 + xc) << 8) + (ch << 6) + ci];
            lds[e] = v;
        }
        __syncthreads();
        #pragma unroll
        for (int ky = 0; ky < 3; ky++) {
            for (int ci4 = 0; ci4 < 16; ci4++) {
                float4 w0 = fwT4[((ky * 3 + 0) * 64 + ch * 16 + ci4) * 64 + co];
                float4 w1 = fwT4[((ky * 3 + 1) * 64 + ch * 16 + ci4) * 64 + co];
                float4 w2 = fwT4[((ky * 3 + 2) * 64 + ch * 16 + ci4) * 64 + co];
                float4 iv[10];
                #pragma unroll
                for (int u = 0; u < 10; u++)
                    iv[u] = *(const float4*)&lds[(ky * 34 + px0 + u) * 64 + ci4 * 4];
                #pragma unroll
                for (int j = 0; j < 8; j++) {
                    acc[j] += w0.x * iv[j].x + w0.y * iv[j].y + w0.z * iv[j].z + w0.w * iv[j].w
                            + w1.x * iv[j + 1].x + w1.y * iv[j + 1].y + w1.z * iv[j + 1].z + w1.w * iv[j + 1].w
                            + w2.x * iv[j + 2].x + w2.y * iv[j + 2].y + w2.z * iv[j + 2].z + w2.w * iv[j + 2].w;
                }
            }
        }
    }
    __syncthreads();
    #pragma unroll
    for (int j = 0; j < 8; j++) lds[co * 33 + px0 + j] = acc[j];   // padded: conflict-free
    __syncthreads();
    int px2 = t & 31, cg0 = t >> 5;
    #pragma unroll
    for (int rep = 0; rep < 8; rep++) {
        int co2 = cg0 * 8 + rep;
        float v = lds[co2 * 33 + px2] + fb[co2];
        out[((b * 64 + co2) * 96 + y) * 96 + x0 + px2] = v > 0.f ? v : 0.f;
    }
}

extern "C" void kernel_launch(void* const* d_in, const int* in_sizes, int n_in,
                              void* d_out, int out_size, void* d_ws, size_t ws_size,
                              hipStream_t stream) {
    const float* sup = (const float*)d_in[0];
    const float* key = (const float*)d_in[1];
    const float* smw = (const float*)d_in[2];
    const float* smb = (const float*)d_in[3];
    const float* rw  = (const float*)d_in[4];
    const float* rb  = (const float*)d_in[5];
    const float *vw[3], *vb[3], *rpb[3];
    if (in_sizes[8] == 25) {   // setup_inputs() dict order: (v_w, v_b, rpb) per level
        for (int l = 0; l < 3; l++) {
            vw[l]  = (const float*)d_in[6 + 3 * l];
            vb[l]  = (const float*)d_in[7 + 3 * l];
            rpb[l] = (const float*)d_in[8 + 3 * l];
        }
    } else {                   // signature order fallback
        for (int l = 0; l < 3; l++) {
            vw[l]  = (const float*)d_in[6 + 2 * l];
            vb[l]  = (const float*)d_in[7 + 2 * l];
            rpb[l] = (const float*)d_in[12 + l];
        }
    }
    const float* fw = (const float*)d_in[15];
    const float* fb = (const float*)d_in[16];
    float* out = (float*)d_out;

    float* wsf    = (float*)d_ws;
    float* smooth = wsf;                    // 2359296
    float* sup2   = wsf + 2359296;          // 2359296 (NHWC)
    float* qT     = wsf + 4718592;          // 2359296 (NHWC)
    float* fused  = wsf + 7077888;          // 9437184 (NHWC, 256ch)
    float* rwT    = wsf + 16515072;         // 8192
    float* vwT    = wsf + 16523264;         // 12288
    float* fwT    = wsf + 16535552;         // 147456

    prep_weights<<<dim3(656), dim3(256), 0, stream>>>(rw, vw[0], vw[1], vw[2], fw, rwT, vwT, fwT);
    pack_kernel<<<dim3(3, 2, 384), dim3(32, 8), 0, stream>>>(key, sup, qT, fused);
    shift_smooth<<<dim3(9216), dim3(256), 0, stream>>>(sup, smw, smb, smooth);
    reduce_kernel<<<dim3(9216), dim3(256), 0, stream>>>(sup, smooth, rwT, rb, sup2);
    natten_kernel<3><<<dim3(36864), dim3(64), 0, stream>>>(qT, sup2, vwT,        vb[0], rpb[0], fused, 0);
    natten_kernel<5><<<dim3(36864), dim3(64), 0, stream>>>(qT, sup2, vwT + 4096, vb[1], rpb[1], fused, 1);
    natten_kernel<7><<<dim3(36864), dim3(64), 0, stream>>>(qT, sup2, vwT + 8192, vb[2], rpb[2], fused, 2);
    fusion_kernel<<<dim3(3, 96, 4), dim3(256), 0, stream>>>(fused, fwT, fb, out);
}

// Round 2
// 458.647 us; speedup vs baseline: 1.4222x; 1.4222x over previous
//
#include <hip/hip_runtime.h>
#include <hip/hip_bf16.h>

#define HW 9216
#define NPX 36864

typedef __attribute__((ext_vector_type(8))) short short8;
typedef __attribute__((ext_vector_type(4))) float f32x4;

// ---------- weight pre-transposes ----------
__global__ __launch_bounds__(256) void prep_weights(
    const float* __restrict__ rw, const float* __restrict__ vw0,
    const float* __restrict__ vw1, const float* __restrict__ vw2,
    const float* __restrict__ fw,
    float* __restrict__ rwT, float* __restrict__ vwT, __hip_bfloat16* __restrict__ fwB)
{
    int idx = blockIdx.x * 256 + threadIdx.x;
    if (idx < 8192) {                       // reduce_w (64,128) -> rwT[i][c]
        int c = idx & 63, i = idx >> 6;
        rwT[idx] = rw[c * 128 + i];
    } else if (idx < 20480) {               // v_w[lvl] (64,64) -> vwT[lvl][i][c]
        int e = idx - 8192;
        int lvl = e >> 12, r = e & 4095;
        int c = r & 63, i = r >> 6;
        const float* vw = (lvl == 0) ? vw0 : ((lvl == 1) ? vw1 : vw2);
        vwT[e] = vw[c * 64 + i];
    } else if (idx < 167936) {              // fusion_w (64,256,3,3) -> fwB[co][tap*256+ci] bf16
        int e = idx - 20480;
        int ci = e & 255, tmp = e >> 8;
        int tap = tmp % 9, co = tmp / 9;
        fwB[e] = __hip_bfloat16(fw[co * 2304 + ci * 9 + tap]);
    }
}

// ---------- transpose key->qT (NHWC fp32) and sup->fused[ch 0:64] (bf16) ----------
__global__ void pack_kernel(const float* __restrict__ key, const float* __restrict__ sup,
                            float* __restrict__ qT, __hip_bfloat16* __restrict__ fused)
{
    __shared__ float lk[32][33], ls[32][33];
    int tx = threadIdx.x, ty = threadIdx.y;
    int x0 = blockIdx.x * 32, c0 = blockIdx.y * 32;
    int z = blockIdx.z; int b = z / 96, y = z - b * 96;
    #pragma unroll
    for (int i = 0; i < 32; i += 8) {
        int c = c0 + ty + i;
        lk[ty + i][tx] = key[((b * 64 + c) * 96 + y) * 96 + x0 + tx];
        ls[ty + i][tx] = sup[((b * 64 + c) * 96 + y) * 96 + x0 + tx];
    }
    __syncthreads();
    #pragma unroll
    for (int i = 0; i < 32; i += 8) {
        int px = (b * 96 + y) * 96 + x0 + ty + i;
        qT[px * 64 + c0 + tx]     = lk[tx][ty + i];
        fused[px * 256 + c0 + tx] = __hip_bfloat16(ls[tx][ty + i]);
    }
}

// ---------- shifted grouped 3x3 conv (shift folded into index math) ----------
__global__ __launch_bounds__(256) void shift_smooth(const float* __restrict__ sup,
    const float* __restrict__ w, const float* __restrict__ bias, float* __restrict__ smooth)
{
    int idx = blockIdx.x * 256 + threadIdx.x;        // < 2359296
    int x = idx % 96; int t1 = idx / 96; int y = t1 % 96; int t2 = t1 / 96;
    int c = t2 & 63; int b = t2 >> 6;
    int g = c >> 3;
    int sh = 3 * ((g >= 5) - (g < 3));
    int m = (g < 3) ? g : ((g < 5) ? ((g == 3) ? 0 : 2) : (g - 5));
    int sw = 3 * m - 3;

    float acc = bias[c];
    const float* wp = w + c * 72;
    for (int ic = 0; ic < 8; ic++) {
        const float* sp = sup + ((b * 64 + g * 8 + ic) * 96) * 96;
        #pragma unroll
        for (int ky = 0; ky < 3; ky++)
            #pragma unroll
            for (int kx = 0; kx < 3; kx++) {
                int yy = y + ky - 1, xx = x + kx - 1;
                int ys = yy - sh, xs = xx - sw;
                float v = 0.f;
                if (yy >= 0 && yy < 96 && xx >= 0 && xx < 96 &&
                    ys >= 0 && ys < 96 && xs >= 0 && xs < 96)
                    v = sp[ys * 96 + xs];
                acc += wp[ic * 9 + ky * 3 + kx] * v;
            }
    }
    smooth[idx] = acc;
}

// ---------- 1x1 reduce conv (128->64), writes sup2 in NHWC ----------
__global__ __launch_bounds__(256) void reduce_kernel(const float* __restrict__ sup,
    const float* __restrict__ smooth, const float* __restrict__ rwT,
    const float* __restrict__ rb, float* __restrict__ sup2)
{
    int gid = blockIdx.x * 256 + threadIdx.x;
    int c = gid & 63, px = gid >> 6;
    int b = px / HW; int rem = px - b * HW;
    const float* s1 = sup + b * 64 * HW + rem;
    const float* s2 = smooth + b * 64 * HW + rem;
    float acc = rb[c];
    for (int i = 0; i < 64; i++) {
        acc += rwT[i * 64 + c] * s1[i * HW];
        acc += rwT[(64 + i) * 64 + c] * s2[i * HW];
    }
    sup2[px * 64 + c] = acc;
}

// ---------- neighborhood attention (one wave per pixel); v-conv folded in ----------
template<int KS>
__global__ __launch_bounds__(64) void natten_kernel(
    const float* __restrict__ qT, const float* __restrict__ k,   // k = sup2 (NHWC)
    const float* __restrict__ vwT, const float* __restrict__ vb,
    const float* __restrict__ rpb, __hip_bfloat16* __restrict__ fused, int lvl)
{
    constexpr int R = KS / 2, KK = KS * KS, NB = 2 * KS - 1;
    constexpr int NSET = (KK + 7) / 8;
    int lane = threadIdx.x;
    int px = blockIdx.x;
    int b = px / HW; int rem = px - b * HW;
    int y = rem / 96, x = rem - (rem / 96) * 96;
    int ni = y - R; if (ni < 0) ni = 0; if (ni > 96 - KS) ni = 96 - KS;
    int nj = x - R; if (nj < 0) nj = 0; if (nj > 96 - KS) nj = 96 - KS;
    int pi = KS - 1 + ni - y, pj = KS - 1 + nj - x;

    __shared__ __align__(16) float q_lds[64];
    __shared__ float s_lds[64], s2_lds[64];
    q_lds[lane] = qT[px * 64 + lane];
    __syncthreads();

    int cg = lane >> 3, pq = lane & 7;
    float4 qa = *(const float4*)&q_lds[cg * 8];
    float4 qb = *(const float4*)&q_lds[cg * 8 + 4];
    const float* kbase = k + b * HW * 64;

    // scores: lanes split 8 channel-groups x 8 neighbor-columns
    for (int s = 0; s < NSET; s++) {
        int p = s * 8 + pq;
        float partial = 0.f;
        int ky = 0, kx = 0;
        bool act = (p < KK);
        if (act) {
            ky = p / KS; kx = p - ky * KS;
            const float* kp = kbase + ((ni + ky) * 96 + nj + kx) * 64 + cg * 8;
            float4 ka = *(const float4*)kp;
            float4 kb2 = *(const float4*)(kp + 4);
            partial = qa.x * ka.x + qa.y * ka.y + qa.z * ka.z + qa.w * ka.w
                    + qb.x * kb2.x + qb.y * kb2.y + qb.z * kb2.z + qb.w * kb2.w;
        }
        partial += __shfl_xor(partial, 8);
        partial += __shfl_xor(partial, 16);
        partial += __shfl_xor(partial, 32);
        if (act && cg == 0)
            s_lds[p] = partial + rpb[(pi + ky) * NB + pj + kx];
    }
    __syncthreads();

    // softmax across KK entries (single wave)
    float val = (lane < KK) ? s_lds[lane] : -1e30f;
    float mx = val;
    #pragma unroll
    for (int off = 32; off; off >>= 1) mx = fmaxf(mx, __shfl_xor(mx, off));
    float e = (lane < KK) ? __expf(val - mx) : 0.f;
    float ss = e;
    #pragma unroll
    for (int off = 32; off; off >>= 1) ss += __shfl_xor(ss, off);
    if (lane < KK) s_lds[lane] = e / ss;
    __syncthreads();

    // aggregate sup2 with attn weights (v-conv commutes past softmax: sum(attn)=1)
    float sacc = 0.f;
    #pragma unroll
    for (int p = 0; p < KK; p++) {
        int ky = p / KS, kx = p - (p / KS) * KS;
        sacc += s_lds[p] * kbase[((ni + ky) * 96 + nj + kx) * 64 + lane];
    }
    s2_lds[lane] = sacc;
    __syncthreads();

    // apply v projection: out[c] = vb[c] + sum_i vwT[i][c] * sacc[i]
    float outv = vb[lane];
    for (int i = 0; i < 64; i++)
        outv += vwT[i * 64 + lane] * s2_lds[i];
    fused[px * 256 + (lvl + 1) * 64 + lane] = __hip_bfloat16(outv);
}

// ---------- 3x3 fusion conv (256->64) as implicit-GEMM bf16 MFMA + bias + relu ----------
// A: M=pixels, K=(tap,ci); B: fwB[co][tap*256+ci]; mfma_f32_16x16x32_bf16
// wave = 2 m-tiles (32 px) x 4 n-tiles (64 co); block = 2 waves (64 px)
__global__ __launch_bounds__(128) void fusion_mfma(
    const __hip_bfloat16* __restrict__ fB, const __hip_bfloat16* __restrict__ fwB,
    const float* __restrict__ fb, float* __restrict__ out)
{
    __shared__ float lds_out[64 * 66];
    int t = threadIdx.x;
    int l = t & 63, wv = t >> 6;
    int lm = l & 15, quad = l >> 4;
    int pxbase = blockIdx.x * 64 + wv * 32;

    // per-lane pixel for each m-tile
    int px0 = pxbase + lm, px1 = pxbase + 16 + lm;
    int b = px0 / HW;
    int rem0 = px0 - b * HW, rem1 = px1 - b * HW;
    int y0 = rem0 / 96, x0 = rem0 - y0 * 96;
    int y1 = rem1 / 96, x1 = rem1 - y1 * 96;

    f32x4 acc[2][4] = {};

    // B pointers: n-tile nt covers co = nt*16 + lm
    const __hip_bfloat16* bp = fwB + lm * 2304 + quad * 8;

    #pragma unroll
    for (int ky = 0; ky < 3; ky++) {
        int yy0 = y0 + ky - 1, yy1 = y1 + ky - 1;
        #pragma unroll
        for (int kx = 0; kx < 3; kx++) {
            int xx0 = x0 + kx - 1, xx1 = x1 + kx - 1;
            bool ok0 = (yy0 >= 0) & (yy0 < 96) & (xx0 >= 0) & (xx0 < 96);
            bool ok1 = (yy1 >= 0) & (yy1 < 96) & (xx1 >= 0) & (xx1 < 96);
            const __hip_bfloat16* ap0 = fB + ((size_t)(b * HW + (ok0 ? (yy0 * 96 + xx0) : 0)) << 8) + quad * 8;
            const __hip_bfloat16* ap1 = fB + ((size_t)(b * HW + (ok1 ? (yy1 * 96 + xx1) : 0)) << 8) + quad * 8;
            int tap = (ky * 3 + kx) * 256;
            #pragma unroll 2
            for (int ci = 0; ci < 256; ci += 32) {
                short8 a0 = {}, a1 = {};
                if (ok0) a0 = *(const short8*)(ap0 + ci);
                if (ok1) a1 = *(const short8*)(ap1 + ci);
                short8 b0 = *(const short8*)(bp + tap + ci);
                short8 b1 = *(const short8*)(bp + 16 * 2304 + tap + ci);
                short8 b2 = *(const short8*)(bp + 32 * 2304 + tap + ci);
                short8 b3 = *(const short8*)(bp + 48 * 2304 + tap + ci);
                acc[0][0] = __builtin_amdgcn_mfma_f32_16x16x32_bf16(a0, b0, acc[0][0], 0, 0, 0);
                acc[0][1] = __builtin_amdgcn_mfma_f32_16x16x32_bf16(a0, b1, acc[0][1], 0, 0, 0);
                acc[0][2] = __builtin_amdgcn_mfma_f32_16x16x32_bf16(a0, b2, acc[0][2], 0, 0, 0);
                acc[0][3] = __builtin_amdgcn_mfma_f32_16x16x32_bf16(a0, b3, acc[0][3], 0, 0, 0);
                acc[1][0] = __builtin_amdgcn_mfma_f32_16x16x32_bf16(a1, b0, acc[1][0], 0, 0, 0);
                acc[1][1] = __builtin_amdgcn_mfma_f32_16x16x32_bf16(a1, b1, acc[1][1], 0, 0, 0);
                acc[1][2] = __builtin_amdgcn_mfma_f32_16x16x32_bf16(a1, b2, acc[1][2], 0, 0, 0);
                acc[1][3] = __builtin_amdgcn_mfma_f32_16x16x32_bf16(a1, b3, acc[1][3], 0, 0, 0);
            }
        }
    }

    // epilogue: C/D layout col=lane&15 (co within n-tile), row=quad*4+reg (m within m-tile)
    #pragma unroll
    for (int mt = 0; mt < 2; mt++)
        #pragma unroll
        for (int nt = 0; nt < 4; nt++)
            #pragma unroll
            for (int r = 0; r < 4; r++) {
                int row = wv * 32 + mt * 16 + quad * 4 + r;
                int co = nt * 16 + lm;
                lds_out[co * 66 + row] = acc[mt][nt][r];
            }
    __syncthreads();

    int pxr = blockIdx.x * 64 + (t & 63);
    int br = pxr / HW; int remr = pxr - br * HW;
    #pragma unroll 4
    for (int i = 0; i < 32; i++) {
        int co = (t >> 6) * 32 + i;
        float v = lds_out[co * 66 + (t & 63)] + fb[co];
        out[(br * 64 + co) * HW + remr] = v > 0.f ? v : 0.f;
    }
}

extern "C" void kernel_launch(void* const* d_in, const int* in_sizes, int n_in,
                              void* d_out, int out_size, void* d_ws, size_t ws_size,
                              hipStream_t stream) {
    const float* sup = (const float*)d_in[0];
    const float* key = (const float*)d_in[1];
    const float* smw = (const float*)d_in[2];
    const float* smb = (const float*)d_in[3];
    const float* rw  = (const float*)d_in[4];
    const float* rb  = (const float*)d_in[5];
    const float *vw[3], *vb[3], *rpb[3];
    if (in_sizes[8] == 25) {   // setup_inputs() dict order: (v_w, v_b, rpb) per level
        for (int l = 0; l < 3; l++) {
            vw[l]  = (const float*)d_in[6 + 3 * l];
            vb[l]  = (const float*)d_in[7 + 3 * l];
            rpb[l] = (const float*)d_in[8 + 3 * l];
        }
    } else {                   // signature order fallback
        for (int l = 0; l < 3; l++) {
            vw[l]  = (const float*)d_in[6 + 2 * l];
            vb[l]  = (const float*)d_in[7 + 2 * l];
            rpb[l] = (const float*)d_in[12 + l];
        }
    }
    const float* fw = (const float*)d_in[15];
    const float* fb = (const float*)d_in[16];
    float* out = (float*)d_out;

    float* wsf    = (float*)d_ws;
    float* smooth = wsf;                                   // 2359296 f
    float* sup2   = wsf + 2359296;                         // 2359296 f (NHWC)
    float* qT     = wsf + 4718592;                         // 2359296 f (NHWC)
    float* rwT    = wsf + 7077888;                         // 8192 f
    float* vwT    = wsf + 7086080;                         // 12288 f
    __hip_bfloat16* fusedB = (__hip_bfloat16*)(wsf + 7098368);   // 9437184 bf16
    __hip_bfloat16* fwB    = (__hip_bfloat16*)(wsf + 11816960);  // 147456 bf16

    prep_weights<<<dim3(656), dim3(256), 0, stream>>>(rw, vw[0], vw[1], vw[2], fw, rwT, vwT, fwB);
    pack_kernel<<<dim3(3, 2, 384), dim3(32, 8), 0, stream>>>(key, sup, qT, fusedB);
    shift_smooth<<<dim3(9216), dim3(256), 0, stream>>>(sup, smw, smb, smooth);
    reduce_kernel<<<dim3(9216), dim3(256), 0, stream>>>(sup, smooth, rwT, rb, sup2);
    natten_kernel<3><<<dim3(36864), dim3(64), 0, stream>>>(qT, sup2, vwT,        vb[0], rpb[0], fusedB, 0);
    natten_kernel<5><<<dim3(36864), dim3(64), 0, stream>>>(qT, sup2, vwT + 4096, vb[1], rpb[1], fusedB, 1);
    natten_kernel<7><<<dim3(36864), dim3(64), 0, stream>>>(qT, sup2, vwT + 8192, vb[2], rpb[2], fusedB, 2);
    fusion_mfma<<<dim3(576), dim3(128), 0, stream>>>(fusedB, fwB, fb, out);
}

// Round 3
// 352.933 us; speedup vs baseline: 1.8482x; 1.2995x over previous
//
#include <hip/hip_runtime.h>
#include <hip/hip_bf16.h>

#define HW 9216
#define NPX 36864

typedef __attribute__((ext_vector_type(8))) short short8;
typedef __attribute__((ext_vector_type(4))) float f32x4;

static __device__ __forceinline__ unsigned short f2bf(float x) {
    union { __hip_bfloat16 h; unsigned short u; } c; c.h = __float2bfloat16(x); return c.u;
}
static __device__ __forceinline__ float bfl(unsigned int u){ return __uint_as_float(u << 16); }
static __device__ __forceinline__ float bfh(unsigned int u){ return __uint_as_float(u & 0xffff0000u); }

// ---------- weight pre-transposes ----------
__global__ __launch_bounds__(256) void prep_weights(
    const float* __restrict__ rw, const float* __restrict__ vw0,
    const float* __restrict__ vw1, const float* __restrict__ vw2,
    const float* __restrict__ fw,
    float* __restrict__ rwT, unsigned short* __restrict__ vwF, __hip_bfloat16* __restrict__ fwB)
{
    int idx = blockIdx.x * 256 + threadIdx.x;
    if (idx < 8192) {                       // reduce_w (64,128) -> rwT[i][c]
        int c = idx & 63, i = idx >> 6;
        rwT[idx] = rw[c * 128 + i];
    } else if (idx < 20480) {               // v_w -> MFMA B-fragment order vwF[lvl][nt][kf][lane][j]
        int e = idx - 8192;
        int j = e & 7, lane = (e >> 3) & 63, kf = (e >> 9) & 1, nt = (e >> 10) & 3, lvl = e >> 12;
        int co = nt * 16 + (lane & 15);
        int k = kf * 32 + (lane >> 4) * 8 + j;
        const float* vw = (lvl == 0) ? vw0 : ((lvl == 1) ? vw1 : vw2);
        vwF[e] = f2bf(vw[co * 64 + k]);
    } else if (idx < 167936) {              // fusion_w (64,256,3,3) -> fwB[co][tap*256+ci] bf16
        int e = idx - 20480;
        int ci = e & 255, tmp = e >> 8;
        int tap = tmp % 9, co = tmp / 9;
        fwB[e] = __hip_bfloat16(fw[co * 2304 + ci * 9 + tap]);
    }
}

// ---------- transpose key->qT (NHWC fp32) and sup->fused[ch 0:64] (bf16) ----------
__global__ void pack_kernel(const float* __restrict__ key, const float* __restrict__ sup,
                            float* __restrict__ qT, __hip_bfloat16* __restrict__ fused)
{
    __shared__ float lk[32][33], ls[32][33];
    int tx = threadIdx.x, ty = threadIdx.y;
    int x0 = blockIdx.x * 32, c0 = blockIdx.y * 32;
    int z = blockIdx.z; int b = z / 96, y = z - b * 96;
    #pragma unroll
    for (int i = 0; i < 32; i += 8) {
        int c = c0 + ty + i;
        lk[ty + i][tx] = key[((b * 64 + c) * 96 + y) * 96 + x0 + tx];
        ls[ty + i][tx] = sup[((b * 64 + c) * 96 + y) * 96 + x0 + tx];
    }
    __syncthreads();
    #pragma unroll
    for (int i = 0; i < 32; i += 8) {
        int px = (b * 96 + y) * 96 + x0 + ty + i;
        qT[px * 64 + c0 + tx]     = lk[tx][ty + i];
        fused[px * 256 + c0 + tx] = __hip_bfloat16(ls[tx][ty + i]);
    }
}

// ---------- shifted grouped 3x3 conv: 4 x-consecutive outputs per thread ----------
__global__ __launch_bounds__(256) void shift_smooth(const float* __restrict__ sup,
    const float* __restrict__ w, const float* __restrict__ bias, float* __restrict__ smooth)
{
    int g = blockIdx.x * 256 + threadIdx.x;          // < 589824
    int xq = g % 24; int r1 = g / 24;
    int c = r1 & 63; int r2 = r1 >> 6;
    int y = r2 % 96; int b = r2 / 96;
    int x0 = xq * 4;
    int grp = c >> 3;
    int sh = 3 * ((grp >= 5) - (grp < 3));
    int m = (grp < 3) ? grp : ((grp < 5) ? ((grp == 3) ? 0 : 2) : (grp - 5));
    int sw = 3 * m - 3;

    float bz = bias[c];
    float acc[4] = {bz, bz, bz, bz};
    const float* wp = w + c * 72;
    for (int ic = 0; ic < 8; ic++) {
        const float* sp = sup + (size_t)(b * 64 + grp * 8 + ic) * HW;
        float wreg[9];
        #pragma unroll
        for (int q = 0; q < 9; q++) wreg[q] = wp[ic * 9 + q];
        #pragma unroll
        for (int ky = 0; ky < 3; ky++) {
            int yy = y + ky - 1;
            int ys = yy - sh;
            bool rowok = (yy >= 0) & (yy < 96) & (ys >= 0) & (ys < 96);
            float v[6];
            #pragma unroll
            for (int u = 0; u < 6; u++) {
                int xx = x0 + u - 1, xs = xx - sw;
                bool ok = rowok & (xx >= 0) & (xx < 96) & (xs >= 0) & (xs < 96);
                v[u] = ok ? sp[ys * 96 + xs] : 0.f;
            }
            #pragma unroll
            for (int j = 0; j < 4; j++)
                acc[j] += wreg[ky*3]*v[j] + wreg[ky*3+1]*v[j+1] + wreg[ky*3+2]*v[j+2];
        }
    }
    float4 st = {acc[0], acc[1], acc[2], acc[3]};
    *(float4*)&smooth[((size_t)(b * 64 + c) * 96 + y) * 96 + x0] = st;
}

// ---------- 1x1 reduce conv (128->64): px per lane, 16 co per thread ----------
__global__ __launch_bounds__(256) void reduce_kernel(const float* __restrict__ sup,
    const float* __restrict__ smooth, const float* __restrict__ rwT,
    const float* __restrict__ rb, float* __restrict__ sup2)
{
    int t = threadIdx.x;
    int lane = t & 63, wq = t >> 6;          // wq: wave-uniform channel quarter
    int px = blockIdx.x * 64 + lane;
    int b = px / HW; int rem = px - b * HW;
    const float* s1 = sup + (size_t)b * 64 * HW + rem;
    const float* s2 = smooth + (size_t)b * 64 * HW + rem;
    float acc[16];
    #pragma unroll
    for (int j = 0; j < 16; j++) acc[j] = rb[wq * 16 + j];
    for (int i = 0; i < 64; i++) {
        float v = s1[i * HW];
        #pragma unroll
        for (int j = 0; j < 16; j++) acc[j] += rwT[i * 64 + wq * 16 + j] * v;
    }
    for (int i = 0; i < 64; i++) {
        float v = s2[i * HW];
        #pragma unroll
        for (int j = 0; j < 16; j++) acc[j] += rwT[(64 + i) * 64 + wq * 16 + j] * v;
    }
    float* op = sup2 + (size_t)px * 64 + wq * 16;
    #pragma unroll
    for (int j = 0; j < 16; j += 4) { float4 st = {acc[j], acc[j+1], acc[j+2], acc[j+3]}; *(float4*)(op + j) = st; }
}

// ---------- fused 3-level neighborhood attention ----------
// block = 8x8 px tile, 256 threads (4 per px). Shared 49 dots; nested windows.
template<int KS>
__device__ __forceinline__ void level_softmax(int qc, int y, int x, int ni7, int nj7,
        const float* __restrict__ rpb, const float* dots_row, float* out_row)
{
    constexpr int R = KS / 2, KK = KS * KS, NB = 2 * KS - 1;
    constexpr int NE = (KK + 3) / 4;
    int ni = min(max(y - R, 0), 96 - KS), nj = min(max(x - R, 0), 96 - KS);
    int di = ni - ni7, dj = nj - nj7;
    int br = KS - 1 + ni - y, bc = KS - 1 + nj - x;
    float sv[NE];
    float mx = -1e30f;
    #pragma unroll
    for (int i = 0; i < NE; i++) {
        int e = qc + i * 4;
        if (e < KK) {
            int ey = e / KS, ex = e - ey * KS;
            float s = dots_row[(di + ey) * 7 + dj + ex] + rpb[(br + ey) * NB + bc + ex];
            sv[i] = s; mx = fmaxf(mx, s);
        } else sv[i] = -1e30f;
    }
    mx = fmaxf(mx, __shfl_xor(mx, 1)); mx = fmaxf(mx, __shfl_xor(mx, 2));
    float sum = 0.f;
    #pragma unroll
    for (int i = 0; i < NE; i++) { sv[i] = __expf(sv[i] - mx); sum += sv[i]; }
    sum += __shfl_xor(sum, 1); sum += __shfl_xor(sum, 2);
    float inv = 1.f / sum;
    #pragma unroll
    for (int i = 0; i < NE; i++) {
        int e = qc + i * 4;
        if (e < KK) out_row[e] = sv[i] * inv;
    }
}

__global__ __launch_bounds__(256) void natten_fused(
    const float* __restrict__ qT, const float* __restrict__ sup2,
    const unsigned short* __restrict__ vwF,
    const float* __restrict__ vb0, const float* __restrict__ vb1, const float* __restrict__ vb2,
    const float* __restrict__ rpb0, const float* __restrict__ rpb1, const float* __restrict__ rpb2,
    __hip_bfloat16* __restrict__ fused)
{
    __shared__ __align__(16) unsigned short khalo[196 * 72];  // bf16 k-tile; reused as sproj[3][64][72]
    __shared__ float dots[64][50];
    __shared__ float a3[64][12];
    __shared__ float a5[64][28];

    int t = threadIdx.x;
    int bb = blockIdx.y;
    int tx0 = (blockIdx.x % 12) * 8, ty0 = (blockIdx.x / 12) * 8;
    const float* kb = sup2 + (size_t)bb * HW * 64;

    // stage 14x14x64 k-halo as bf16 (row stride 72 ch: kills 128B bank aliasing)
    for (int it = 0; it < 13; it++) {
        int qidx = it * 256 + t;
        if (qidx < 3136) {
            int cq = qidx & 15, pos = qidx >> 4;
            int py = pos / 14, pxx = pos - py * 14;
            int gy = min(max(ty0 - 3 + py, 0), 95);
            int gx = min(max(tx0 - 3 + pxx, 0), 95);
            float4 v = *(const float4*)(kb + (((size_t)gy * 96 + gx) << 6) + cq * 4);
            ushort4 pk = {f2bf(v.x), f2bf(v.y), f2bf(v.z), f2bf(v.w)};
            *(ushort4*)&khalo[pos * 72 + cq * 4] = pk;
        }
    }
    __syncthreads();

    int pxl = t >> 2, qc = t & 3;
    int pty = pxl >> 3, ptx = pxl & 7;
    int y = ty0 + pty, x = tx0 + ptx;
    int gpx = bb * HW + y * 96 + x;

    float qv[16];
    {
        const float* qp = qT + (size_t)gpx * 64 + qc * 16;
        #pragma unroll
        for (int j = 0; j < 16; j += 4) {
            float4 q4 = *(const float4*)(qp + j);
            qv[j] = q4.x; qv[j+1] = q4.y; qv[j+2] = q4.z; qv[j+3] = q4.w;
        }
    }

    int ni7 = min(max(y - 3, 0), 89), nj7 = min(max(x - 3, 0), 89);
    int ly = ni7 - (ty0 - 3), lx = nj7 - (tx0 - 3);

    // 49 shared dot products (q fp32 x k bf16), quad-reduced
    for (int oy = 0; oy < 7; oy++) {
        #pragma unroll
        for (int ox = 0; ox < 7; ox++) {
            const unsigned short* kp = &khalo[((ly + oy) * 14 + lx + ox) * 72 + qc * 16];
            uint4 ka = *(const uint4*)kp;
            uint4 kc = *(const uint4*)(kp + 8);
            float d = qv[0]*bfl(ka.x) + qv[1]*bfh(ka.x) + qv[2]*bfl(ka.y) + qv[3]*bfh(ka.y)
                    + qv[4]*bfl(ka.z) + qv[5]*bfh(ka.z) + qv[6]*bfl(ka.w) + qv[7]*bfh(ka.w)
                    + qv[8]*bfl(kc.x) + qv[9]*bfh(kc.x) + qv[10]*bfl(kc.y) + qv[11]*bfh(kc.y)
                    + qv[12]*bfl(kc.z) + qv[13]*bfh(kc.z) + qv[14]*bfl(kc.w) + qv[15]*bfh(kc.w);
            d += __shfl_xor(d, 1);
            d += __shfl_xor(d, 2);
            if (qc == 0) dots[pxl][oy * 7 + ox] = d;
        }
    }

    // per-level softmax (l7 last: overwrites dots in place). All intra-quad, no barrier.
    level_softmax<3>(qc, y, x, ni7, nj7, rpb0, &dots[pxl][0], &a3[pxl][0]);
    level_softmax<5>(qc, y, x, ni7, nj7, rpb1, &dots[pxl][0], &a5[pxl][0]);
    level_softmax<7>(qc, y, x, ni7, nj7, rpb2, &dots[pxl][0], &dots[pxl][0]);

    int ni5 = min(max(y - 2, 0), 91), nj5 = min(max(x - 2, 0), 91);
    int ni3 = min(max(y - 1, 0), 93), nj3 = min(max(x - 1, 0), 93);
    int di5 = ni5 - ni7, dj5 = nj5 - nj7, di3 = ni3 - ni7, dj3 = nj3 - nj7;

    // aggregation: shared k reads, 3 accumulator sets
    float s2[3][16];
    #pragma unroll
    for (int l = 0; l < 3; l++)
        #pragma unroll
        for (int j = 0; j < 16; j++) s2[l][j] = 0.f;

    for (int oy = 0; oy < 7; oy++) {
        #pragma unroll
        for (int ox = 0; ox < 7; ox++) {
            const unsigned short* kp = &khalo[((ly + oy) * 14 + lx + ox) * 72 + qc * 16];
            uint4 ka = *(const uint4*)kp;
            uint4 kc = *(const uint4*)(kp + 8);
            float kv[16] = {bfl(ka.x), bfh(ka.x), bfl(ka.y), bfh(ka.y),
                            bfl(ka.z), bfh(ka.z), bfl(ka.w), bfh(ka.w),
                            bfl(kc.x), bfh(kc.x), bfl(kc.y), bfh(kc.y),
                            bfl(kc.z), bfh(kc.z), bfl(kc.w), bfh(kc.w)};
            float w7 = dots[pxl][oy * 7 + ox];
            #pragma unroll
            for (int j = 0; j < 16; j++) s2[2][j] += w7 * kv[j];
            int e5y = oy - di5, e5x = ox - dj5;
            if ((unsigned)e5y < 5u && (unsigned)e5x < 5u) {
                float w5 = a5[pxl][e5y * 5 + e5x];
                #pragma unroll
                for (int j = 0; j < 16; j++) s2[1][j] += w5 * kv[j];
            }
            int e3y = oy - di3, e3x = ox - dj3;
            if ((unsigned)e3y < 3u && (unsigned)e3x < 3u) {
                float w3 = a3[pxl][e3y * 3 + e3x];
                #pragma unroll
                for (int j = 0; j < 16; j++) s2[0][j] += w3 * kv[j];
            }
        }
    }
    __syncthreads();   // khalo reads done -> reuse as sproj

    unsigned short* sproj = khalo;   // [lvl*64+pxl][72]
    #pragma unroll
    for (int l = 0; l < 3; l++) {
        unsigned int pk[8];
        #pragma unroll
        for (int j = 0; j < 8; j++)
            pk[j] = (unsigned int)f2bf(s2[l][2*j]) | ((unsigned int)f2bf(s2[l][2*j+1]) << 16);
        unsigned int* dst = (unsigned int*)&sproj[(l * 64 + pxl) * 72 + qc * 16];
        uint4 s0 = {pk[0], pk[1], pk[2], pk[3]};
        uint4 s1 = {pk[4], pk[5], pk[6], pk[7]};
        *(uint4*)dst = s0;
        *(uint4*)(dst + 4) = s1;
    }
    __syncthreads();

    // v-projection per level: 64x64x64 GEMM via mfma_f32_16x16x32_bf16
    int wv = t >> 6, lane = t & 63;
    int lm = lane & 15, quad = lane >> 4;
    #pragma unroll
    for (int l = 0; l < 3; l++) {
        f32x4 acc[4];
        #pragma unroll
        for (int nt = 0; nt < 4; nt++) acc[nt] = (f32x4){0.f, 0.f, 0.f, 0.f};
        #pragma unroll
        for (int kf = 0; kf < 2; kf++) {
            short8 a = *(const short8*)&sproj[(l * 64 + wv * 16 + lm) * 72 + kf * 32 + quad * 8];
            #pragma unroll
            for (int nt = 0; nt < 4; nt++) {
                short8 bfr = *(const short8*)&vwF[(((l * 4 + nt) * 2 + kf) * 64 + lane) * 8];
                acc[nt] = __builtin_amdgcn_mfma_f32_16x16x32_bf16(a, bfr, acc[nt], 0, 0, 0);
            }
        }
        const float* vbl = (l == 0) ? vb0 : ((l == 1) ? vb1 : vb2);
        #pragma unroll
        for (int nt = 0; nt < 4; nt++)
            #pragma unroll
            for (int r = 0; r < 4; r++) {
                int p = wv * 16 + quad * 4 + r;
                int co = nt * 16 + lm;
                int py = p >> 3, pxx = p & 7;
                size_t off = ((size_t)(bb * HW + (ty0 + py) * 96 + tx0 + pxx) << 8) + (l + 1) * 64 + co;
                fused[off] = __hip_bfloat16(acc[nt][r] + vbl[co]);
            }
    }
}

// ---------- 3x3 fusion conv (256->64) as implicit-GEMM bf16 MFMA + bias + relu ----------
__global__ __launch_bounds__(128) void fusion_mfma(
    const __hip_bfloat16* __restrict__ fB, const __hip_bfloat16* __restrict__ fwB,
    const float* __restrict__ fb, float* __restrict__ out)
{
    __shared__ float lds_out[64 * 66];
    int t = threadIdx.x;
    int l = t & 63, wv = t >> 6;
    int lm = l & 15, quad = l >> 4;
    int pxbase = blockIdx.x * 64 + wv * 32;

    int px0 = pxbase + lm, px1 = pxbase + 16 + lm;
    int b = px0 / HW;
    int rem0 = px0 - b * HW, rem1 = px1 - b * HW;
    int y0 = rem0 / 96, x0 = rem0 - y0 * 96;
    int y1 = rem1 / 96, x1 = rem1 - y1 * 96;

    f32x4 acc[2][4] = {};
    const __hip_bfloat16* bp = fwB + lm * 2304 + quad * 8;

    #pragma unroll
    for (int ky = 0; ky < 3; ky++) {
        int yy0 = y0 + ky - 1, yy1 = y1 + ky - 1;
        #pragma unroll
        for (int kx = 0; kx < 3; kx++) {
            int xx0 = x0 + kx - 1, xx1 = x1 + kx - 1;
            bool ok0 = (yy0 >= 0) & (yy0 < 96) & (xx0 >= 0) & (xx0 < 96);
            bool ok1 = (yy1 >= 0) & (yy1 < 96) & (xx1 >= 0) & (xx1 < 96);
            const __hip_bfloat16* ap0 = fB + ((size_t)(b * HW + (ok0 ? (yy0 * 96 + xx0) : 0)) << 8) + quad * 8;
            const __hip_bfloat16* ap1 = fB + ((size_t)(b * HW + (ok1 ? (yy1 * 96 + xx1) : 0)) << 8) + quad * 8;
            int tap = (ky * 3 + kx) * 256;
            #pragma unroll 2
            for (int ci = 0; ci < 256; ci += 32) {
                short8 a0 = {}, a1 = {};
                if (ok0) a0 = *(const short8*)(ap0 + ci);
                if (ok1) a1 = *(const short8*)(ap1 + ci);
                short8 b0 = *(const short8*)(bp + tap + ci);
                short8 b1 = *(const short8*)(bp + 16 * 2304 + tap + ci);
                short8 b2 = *(const short8*)(bp + 32 * 2304 + tap + ci);
                short8 b3 = *(const short8*)(bp + 48 * 2304 + tap + ci);
                acc[0][0] = __builtin_amdgcn_mfma_f32_16x16x32_bf16(a0, b0, acc[0][0], 0, 0, 0);
                acc[0][1] = __builtin_amdgcn_mfma_f32_16x16x32_bf16(a0, b1, acc[0][1], 0, 0, 0);
                acc[0][2] = __builtin_amdgcn_mfma_f32_16x16x32_bf16(a0, b2, acc[0][2], 0, 0, 0);
                acc[0][3] = __builtin_amdgcn_mfma_f32_16x16x32_bf16(a0, b3, acc[0][3], 0, 0, 0);
                acc[1][0] = __builtin_amdgcn_mfma_f32_16x16x32_bf16(a1, b0, acc[1][0], 0, 0, 0);
                acc[1][1] = __builtin_amdgcn_mfma_f32_16x16x32_bf16(a1, b1, acc[1][1], 0, 0, 0);
                acc[1][2] = __builtin_amdgcn_mfma_f32_16x16x32_bf16(a1, b2, acc[1][2], 0, 0, 0);
                acc[1][3] = __builtin_amdgcn_mfma_f32_16x16x32_bf16(a1, b3, acc[1][3], 0, 0, 0);
            }
        }
    }

    #pragma unroll
    for (int mt = 0; mt < 2; mt++)
        #pragma unroll
        for (int nt = 0; nt < 4; nt++)
            #pragma unroll
            for (int r = 0; r < 4; r++) {
                int row = wv * 32 + mt * 16 + quad * 4 + r;
                int co = nt * 16 + lm;
                lds_out[co * 66 + row] = acc[mt][nt][r];
            }
    __syncthreads();

    int pxr = blockIdx.x * 64 + (t & 63);
    int br = pxr / HW; int remr = pxr - br * HW;
    #pragma unroll 4
    for (int i = 0; i < 32; i++) {
        int co = (t >> 6) * 32 + i;
        float v = lds_out[co * 66 + (t & 63)] + fb[co];
        out[(br * 64 + co) * HW + remr] = v > 0.f ? v : 0.f;
    }
}

extern "C" void kernel_launch(void* const* d_in, const int* in_sizes, int n_in,
                              void* d_out, int out_size, void* d_ws, size_t ws_size,
                              hipStream_t stream) {
    const float* sup = (const float*)d_in[0];
    const float* key = (const float*)d_in[1];
    const float* smw = (const float*)d_in[2];
    const float* smb = (const float*)d_in[3];
    const float* rw  = (const float*)d_in[4];
    const float* rb  = (const float*)d_in[5];
    const float *vw[3], *vb[3], *rpb[3];
    if (in_sizes[8] == 25) {
        for (int l = 0; l < 3; l++) {
            vw[l]  = (const float*)d_in[6 + 3 * l];
            vb[l]  = (const float*)d_in[7 + 3 * l];
            rpb[l] = (const float*)d_in[8 + 3 * l];
        }
    } else {
        for (int l = 0; l < 3; l++) {
            vw[l]  = (const float*)d_in[6 + 2 * l];
            vb[l]  = (const float*)d_in[7 + 2 * l];
            rpb[l] = (const float*)d_in[12 + l];
        }
    }
    const float* fw = (const float*)d_in[15];
    const float* fb = (const float*)d_in[16];
    float* out = (float*)d_out;

    float* wsf    = (float*)d_ws;
    float* smooth = wsf;                                    // 2359296 f
    float* sup2   = wsf + 2359296;                          // 2359296 f (NHWC)
    float* qT     = wsf + 4718592;                          // 2359296 f (NHWC)
    float* rwT    = wsf + 7077888;                          // 8192 f
    unsigned short* vwF = (unsigned short*)(wsf + 7086080); // 12288 bf16
    __hip_bfloat16* fusedB = (__hip_bfloat16*)(wsf + 7092224);  // 9437184 bf16
    __hip_bfloat16* fwB    = (__hip_bfloat16*)(wsf + 11810816); // 147456 bf16

    prep_weights<<<dim3(656), dim3(256), 0, stream>>>(rw, vw[0], vw[1], vw[2], fw, rwT, vwF, fwB);
    pack_kernel<<<dim3(3, 2, 384), dim3(32, 8), 0, stream>>>(key, sup, qT, fusedB);
    shift_smooth<<<dim3(2304), dim3(256), 0, stream>>>(sup, smw, smb, smooth);
    reduce_kernel<<<dim3(576), dim3(256), 0, stream>>>(sup, smooth, rwT, rb, sup2);
    natten_fused<<<dim3(144, 4), dim3(256), 0, stream>>>(qT, sup2, vwF,
        vb[0], vb[1], vb[2], rpb[0], rpb[1], rpb[2], fusedB);
    fusion_mfma<<<dim3(576), dim3(128), 0, stream>>>(fusedB, fwB, fb, out);
}

// Round 4
// 295.843 us; speedup vs baseline: 2.2048x; 1.1930x over previous
//
#include <hip/hip_runtime.h>
#include <hip/hip_bf16.h>

#define HW 9216
#define NPX 36864

typedef __attribute__((ext_vector_type(8))) short short8;
typedef __attribute__((ext_vector_type(4))) float f32x4;

static __device__ __forceinline__ unsigned short f2bf(float x) {
    union { __hip_bfloat16 h; unsigned short u; } c; c.h = __float2bfloat16(x); return c.u;
}
static __device__ __forceinline__ float bfl(unsigned int u){ return __uint_as_float(u << 16); }
static __device__ __forceinline__ float bfh(unsigned int u){ return __uint_as_float(u & 0xffff0000u); }

// ---------- weight pre-transposes ----------
__global__ __launch_bounds__(256) void prep_weights(
    const float* __restrict__ rw, const float* __restrict__ vw0,
    const float* __restrict__ vw1, const float* __restrict__ vw2,
    const float* __restrict__ fw,
    float* __restrict__ rwT, unsigned short* __restrict__ vwF, __hip_bfloat16* __restrict__ fwB)
{
    int idx = blockIdx.x * 256 + threadIdx.x;
    if (idx < 8192) {                       // reduce_w (64,128) -> rwT[i][c]
        int c = idx & 63, i = idx >> 6;
        rwT[idx] = rw[c * 128 + i];
    } else if (idx < 20480) {               // v_w -> MFMA B-fragment order vwF[lvl][nt][kf][lane][j]
        int e = idx - 8192;
        int j = e & 7, lane = (e >> 3) & 63, kf = (e >> 9) & 1, nt = (e >> 10) & 3, lvl = e >> 12;
        int co = nt * 16 + (lane & 15);
        int k = kf * 32 + (lane >> 4) * 8 + j;
        const float* vw = (lvl == 0) ? vw0 : ((lvl == 1) ? vw1 : vw2);
        vwF[e] = f2bf(vw[co * 64 + k]);
    } else if (idx < 167936) {              // fusion_w (64,256,3,3) -> fwB[co][tap*256+ci] bf16
        int e = idx - 20480;
        int ci = e & 255, tmp = e >> 8;
        int tap = tmp % 9, co = tmp / 9;
        fwB[e] = __hip_bfloat16(fw[co * 2304 + ci * 9 + tap]);
    }
}

// ---------- transpose key->qT (NHWC fp32) and sup->fused[ch 0:64] (bf16) ----------
__global__ void pack_kernel(const float* __restrict__ key, const float* __restrict__ sup,
                            float* __restrict__ qT, __hip_bfloat16* __restrict__ fused)
{
    __shared__ float lk[32][33], ls[32][33];
    int tx = threadIdx.x, ty = threadIdx.y;
    int x0 = blockIdx.x * 32, c0 = blockIdx.y * 32;
    int z = blockIdx.z; int b = z / 96, y = z - b * 96;
    #pragma unroll
    for (int i = 0; i < 32; i += 8) {
        int c = c0 + ty + i;
        lk[ty + i][tx] = key[((b * 64 + c) * 96 + y) * 96 + x0 + tx];
        ls[ty + i][tx] = sup[((b * 64 + c) * 96 + y) * 96 + x0 + tx];
    }
    __syncthreads();
    #pragma unroll
    for (int i = 0; i < 32; i += 8) {
        int px = (b * 96 + y) * 96 + x0 + ty + i;
        qT[px * 64 + c0 + tx]     = lk[tx][ty + i];
        fused[px * 256 + c0 + tx] = __hip_bfloat16(ls[tx][ty + i]);
    }
}

// ---------- shifted grouped 3x3 conv, LDS-staged, wave-uniform out-channel ----------
// block = (b, grp, 32x32 superblock, c-half): 256 thr. Shift is group-uniform, so the
// shifted+zero-padded 34x34 x 8ic tile is staged once in LDS; each thread does a 4x4
// output tile: 12 ds_read_b128 + 144 FMA per ic. Weights via s_load (c wave-uniform).
__global__ __launch_bounds__(256) void shift_smooth(const float* __restrict__ sup,
    const float* __restrict__ w, const float* __restrict__ bias, float* __restrict__ smooth)
{
    __shared__ __align__(16) float tile[8][34][36];   // 39168 B, row stride 144 B
    int bid = blockIdx.x;                 // 576 = 4b * 8grp * 9sj * 2half
    int half = bid & 1;
    int sj   = (bid >> 1) % 9;
    int grp  = (bid / 18) & 7;
    int b    = bid / 144;
    int sby = sj / 3, sbx = sj % 3;
    int Y0 = sby * 32, X0 = sbx * 32;
    int sh = 3 * ((grp >= 5) - (grp < 3));
    int mm = (grp < 3) ? grp : ((grp < 5) ? ((grp == 3) ? 0 : 2) : (grp - 5));
    int sw = 3 * mm - 3;
    int t = threadIdx.x;

    // stage: tile[ic][r][u] = padded_shift value at (yy=Y0-1+r, xx=X0-1+u)
    const float* supg = sup + (size_t)(b * 64 + grp * 8) * HW;
    #pragma unroll
    for (int pp = 0; pp < 5; pp++) {
        int pos = pp * 256 + t;
        if (pos < 1156) {
            int r = pos / 34, u = pos - r * 34;
            int yy = Y0 - 1 + r, xx = X0 - 1 + u;
            int ys = yy - sh, xs = xx - sw;
            bool ok = (yy >= 0) & (yy < 96) & (xx >= 0) & (xx < 96) &
                      (ys >= 0) & (ys < 96) & (xs >= 0) & (xs < 96);
            int addr = ok ? (ys * 96 + xs) : 0;
            #pragma unroll
            for (int ic = 0; ic < 8; ic++) {
                float v = supg[(size_t)ic * HW + addr];
                tile[ic][r][u] = ok ? v : 0.f;
            }
        }
    }
    __syncthreads();

    int c = __builtin_amdgcn_readfirstlane(grp * 8 + half * 4 + (t >> 6));
    int lane = t & 63;
    int ty4 = lane >> 3, tx4 = lane & 7;          // 8x8 thread tiles of 4x4 px
    int py0 = ty4 * 4, x0r = tx4 * 4;

    float bz = bias[c];
    float acc[4][4];
    #pragma unroll
    for (int jr = 0; jr < 4; jr++)
        #pragma unroll
        for (int j = 0; j < 4; j++) acc[jr][j] = bz;

    const float* wp = w + c * 72;                 // scalar loads (c uniform)
    for (int ic = 0; ic < 8; ic++) {
        float wr[9];
        #pragma unroll
        for (int q = 0; q < 9; q++) wr[q] = wp[ic * 9 + q];
        #pragma unroll
        for (int rr = 0; rr < 6; rr++) {
            // window cols [x0r, x0r+5] of row (py0+rr): two aligned float4s
            float4 fa = *(const float4*)&tile[ic][py0 + rr][x0r];
            float4 fb4 = *(const float4*)&tile[ic][py0 + rr][x0r + 4];
            float f[6] = {fa.x, fa.y, fa.z, fa.w, fb4.x, fb4.y};
            #pragma unroll
            for (int ky = 0; ky < 3; ky++) {
                int jr = rr - ky;
                if (jr >= 0 && jr < 4) {
                    #pragma unroll
                    for (int j = 0; j < 4; j++)
                        acc[jr][j] += wr[ky*3]*f[j] + wr[ky*3+1]*f[j+1] + wr[ky*3+2]*f[j+2];
                }
            }
        }
    }

    float* op = smooth + ((size_t)(b * 64 + c) * 96 + Y0 + py0) * 96 + X0 + x0r;
    #pragma unroll
    for (int jr = 0; jr < 4; jr++) {
        float4 st = {acc[jr][0], acc[jr][1], acc[jr][2], acc[jr][3]};
        *(float4*)(op + (size_t)jr * 96) = st;
    }
}

// ---------- 1x1 reduce conv (128->64): px per lane, 16 co per thread ----------
__global__ __launch_bounds__(256) void reduce_kernel(const float* __restrict__ sup,
    const float* __restrict__ smooth, const float* __restrict__ rwT,
    const float* __restrict__ rb, float* __restrict__ sup2)
{
    int t = threadIdx.x;
    int lane = t & 63, wq = t >> 6;
    int px = blockIdx.x * 64 + lane;
    int b = px / HW; int rem = px - b * HW;
    const float* s1 = sup + (size_t)b * 64 * HW + rem;
    const float* s2 = smooth + (size_t)b * 64 * HW + rem;
    float acc[16];
    #pragma unroll
    for (int j = 0; j < 16; j++) acc[j] = rb[wq * 16 + j];
    for (int i = 0; i < 64; i++) {
        float v = s1[i * HW];
        #pragma unroll
        for (int j = 0; j < 16; j++) acc[j] += rwT[i * 64 + wq * 16 + j] * v;
    }
    for (int i = 0; i < 64; i++) {
        float v = s2[i * HW];
        #pragma unroll
        for (int j = 0; j < 16; j++) acc[j] += rwT[(64 + i) * 64 + wq * 16 + j] * v;
    }
    float* op = sup2 + (size_t)px * 64 + wq * 16;
    #pragma unroll
    for (int j = 0; j < 16; j += 4) { float4 st = {acc[j], acc[j+1], acc[j+2], acc[j+3]}; *(float4*)(op + j) = st; }
}

// ---------- fused 3-level neighborhood attention ----------
template<int KS>
__device__ __forceinline__ void level_softmax(int qc, int y, int x, int ni7, int nj7,
        const float* __restrict__ rpb, const float* dots_row, float* out_row)
{
    constexpr int R = KS / 2, KK = KS * KS, NB = 2 * KS - 1;
    constexpr int NE = (KK + 3) / 4;
    int ni = min(max(y - R, 0), 96 - KS), nj = min(max(x - R, 0), 96 - KS);
    int di = ni - ni7, dj = nj - nj7;
    int br = KS - 1 + ni - y, bc = KS - 1 + nj - x;
    float sv[NE];
    float mx = -1e30f;
    #pragma unroll
    for (int i = 0; i < NE; i++) {
        int e = qc + i * 4;
        if (e < KK) {
            int ey = e / KS, ex = e - ey * KS;
            float s = dots_row[(di + ey) * 7 + dj + ex] + rpb[(br + ey) * NB + bc + ex];
            sv[i] = s; mx = fmaxf(mx, s);
        } else sv[i] = -1e30f;
    }
    mx = fmaxf(mx, __shfl_xor(mx, 1)); mx = fmaxf(mx, __shfl_xor(mx, 2));
    float sum = 0.f;
    #pragma unroll
    for (int i = 0; i < NE; i++) { sv[i] = __expf(sv[i] - mx); sum += sv[i]; }
    sum += __shfl_xor(sum, 1); sum += __shfl_xor(sum, 2);
    float inv = 1.f / sum;
    #pragma unroll
    for (int i = 0; i < NE; i++) {
        int e = qc + i * 4;
        if (e < KK) out_row[e] = sv[i] * inv;
    }
}

__global__ __launch_bounds__(256) void natten_fused(
    const float* __restrict__ qT, const float* __restrict__ sup2,
    const unsigned short* __restrict__ vwF,
    const float* __restrict__ vb0, const float* __restrict__ vb1, const float* __restrict__ vb2,
    const float* __restrict__ rpb0, const float* __restrict__ rpb1, const float* __restrict__ rpb2,
    __hip_bfloat16* __restrict__ fused)
{
    __shared__ __align__(16) unsigned short khalo[196 * 72];  // bf16 k-tile; reused as sproj[3][64][72]
    __shared__ float dots[64][50];
    __shared__ float a3[64][12];
    __shared__ float a5[64][28];

    int t = threadIdx.x;
    int bb = blockIdx.y;
    int tx0 = (blockIdx.x % 12) * 8, ty0 = (blockIdx.x / 12) * 8;
    const float* kb = sup2 + (size_t)bb * HW * 64;

    for (int it = 0; it < 13; it++) {
        int qidx = it * 256 + t;
        if (qidx < 3136) {
            int cq = qidx & 15, pos = qidx >> 4;
            int py = pos / 14, pxx = pos - py * 14;
            int gy = min(max(ty0 - 3 + py, 0), 95);
            int gx = min(max(tx0 - 3 + pxx, 0), 95);
            float4 v = *(const float4*)(kb + (((size_t)gy * 96 + gx) << 6) + cq * 4);
            ushort4 pk = {f2bf(v.x), f2bf(v.y), f2bf(v.z), f2bf(v.w)};
            *(ushort4*)&khalo[pos * 72 + cq * 4] = pk;
        }
    }
    __syncthreads();

    int pxl = t >> 2, qc = t & 3;
    int pty = pxl >> 3, ptx = pxl & 7;
    int y = ty0 + pty, x = tx0 + ptx;
    int gpx = bb * HW + y * 96 + x;

    float qv[16];
    {
        const float* qp = qT + (size_t)gpx * 64 + qc * 16;
        #pragma unroll
        for (int j = 0; j < 16; j += 4) {
            float4 q4 = *(const float4*)(qp + j);
            qv[j] = q4.x; qv[j+1] = q4.y; qv[j+2] = q4.z; qv[j+3] = q4.w;
        }
    }

    int ni7 = min(max(y - 3, 0), 89), nj7 = min(max(x - 3, 0), 89);
    int ly = ni7 - (ty0 - 3), lx = nj7 - (tx0 - 3);

    for (int oy = 0; oy < 7; oy++) {
        #pragma unroll
        for (int ox = 0; ox < 7; ox++) {
            const unsigned short* kp = &khalo[((ly + oy) * 14 + lx + ox) * 72 + qc * 16];
            uint4 ka = *(const uint4*)kp;
            uint4 kc = *(const uint4*)(kp + 8);
            float d = qv[0]*bfl(ka.x) + qv[1]*bfh(ka.x) + qv[2]*bfl(ka.y) + qv[3]*bfh(ka.y)
                    + qv[4]*bfl(ka.z) + qv[5]*bfh(ka.z) + qv[6]*bfl(ka.w) + qv[7]*bfh(ka.w)
                    + qv[8]*bfl(kc.x) + qv[9]*bfh(kc.x) + qv[10]*bfl(kc.y) + qv[11]*bfh(kc.y)
                    + qv[12]*bfl(kc.z) + qv[13]*bfh(kc.z) + qv[14]*bfl(kc.w) + qv[15]*bfh(kc.w);
            d += __shfl_xor(d, 1);
            d += __shfl_xor(d, 2);
            if (qc == 0) dots[pxl][oy * 7 + ox] = d;
        }
    }

    level_softmax<3>(qc, y, x, ni7, nj7, rpb0, &dots[pxl][0], &a3[pxl][0]);
    level_softmax<5>(qc, y, x, ni7, nj7, rpb1, &dots[pxl][0], &a5[pxl][0]);
    level_softmax<7>(qc, y, x, ni7, nj7, rpb2, &dots[pxl][0], &dots[pxl][0]);

    int ni5 = min(max(y - 2, 0), 91), nj5 = min(max(x - 2, 0), 91);
    int ni3 = min(max(y - 1, 0), 93), nj3 = min(max(x - 1, 0), 93);
    int di5 = ni5 - ni7, dj5 = nj5 - nj7, di3 = ni3 - ni7, dj3 = nj3 - nj7;

    float s2[3][16];
    #pragma unroll
    for (int l = 0; l < 3; l++)
        #pragma unroll
        for (int j = 0; j < 16; j++) s2[l][j] = 0.f;

    for (int oy = 0; oy < 7; oy++) {
        #pragma unroll
        for (int ox = 0; ox < 7; ox++) {
            const unsigned short* kp = &khalo[((ly + oy) * 14 + lx + ox) * 72 + qc * 16];
            uint4 ka = *(const uint4*)kp;
            uint4 kc = *(const uint4*)(kp + 8);
            float kv[16] = {bfl(ka.x), bfh(ka.x), bfl(ka.y), bfh(ka.y),
                            bfl(ka.z), bfh(ka.z), bfl(ka.w), bfh(ka.w),
                            bfl(kc.x), bfh(kc.x), bfl(kc.y), bfh(kc.y),
                            bfl(kc.z), bfh(kc.z), bfl(kc.w), bfh(kc.w)};
            float w7 = dots[pxl][oy * 7 + ox];
            #pragma unroll
            for (int j = 0; j < 16; j++) s2[2][j] += w7 * kv[j];
            int e5y = oy - di5, e5x = ox - dj5;
            if ((unsigned)e5y < 5u && (unsigned)e5x < 5u) {
                float w5 = a5[pxl][e5y * 5 + e5x];
                #pragma unroll
                for (int j = 0; j < 16; j++) s2[1][j] += w5 * kv[j];
            }
            int e3y = oy - di3, e3x = ox - dj3;
            if ((unsigned)e3y < 3u && (unsigned)e3x < 3u) {
                float w3 = a3[pxl][e3y * 3 + e3x];
                #pragma unroll
                for (int j = 0; j < 16; j++) s2[0][j] += w3 * kv[j];
            }
        }
    }
    __syncthreads();

    unsigned short* sproj = khalo;
    #pragma unroll
    for (int l = 0; l < 3; l++) {
        unsigned int pk[8];
        #pragma unroll
        for (int j = 0; j < 8; j++)
            pk[j] = (unsigned int)f2bf(s2[l][2*j]) | ((unsigned int)f2bf(s2[l][2*j+1]) << 16);
        unsigned int* dst = (unsigned int*)&sproj[(l * 64 + pxl) * 72 + qc * 16];
        uint4 s0 = {pk[0], pk[1], pk[2], pk[3]};
        uint4 s1 = {pk[4], pk[5], pk[6], pk[7]};
        *(uint4*)dst = s0;
        *(uint4*)(dst + 4) = s1;
    }
    __syncthreads();

    int wv = t >> 6, lane = t & 63;
    int lm = lane & 15, quad = lane >> 4;
    #pragma unroll
    for (int l = 0; l < 3; l++) {
        f32x4 acc[4];
        #pragma unroll
        for (int nt = 0; nt < 4; nt++) acc[nt] = (f32x4){0.f, 0.f, 0.f, 0.f};
        #pragma unroll
        for (int kf = 0; kf < 2; kf++) {
            short8 a = *(const short8*)&sproj[(l * 64 + wv * 16 + lm) * 72 + kf * 32 + quad * 8];
            #pragma unroll
            for (int nt = 0; nt < 4; nt++) {
                short8 bfr = *(const short8*)&vwF[(((l * 4 + nt) * 2 + kf) * 64 + lane) * 8];
                acc[nt] = __builtin_amdgcn_mfma_f32_16x16x32_bf16(a, bfr, acc[nt], 0, 0, 0);
            }
        }
        const float* vbl = (l == 0) ? vb0 : ((l == 1) ? vb1 : vb2);
        #pragma unroll
        for (int nt = 0; nt < 4; nt++)
            #pragma unroll
            for (int r = 0; r < 4; r++) {
                int p = wv * 16 + quad * 4 + r;
                int co = nt * 16 + lm;
                int py = p >> 3, pxx = p & 7;
                size_t off = ((size_t)(bb * HW + (ty0 + py) * 96 + tx0 + pxx) << 8) + (l + 1) * 64 + co;
                fused[off] = __hip_bfloat16(acc[nt][r] + vbl[co]);
            }
    }
}

// ---------- 3x3 fusion conv (256->64) as implicit-GEMM bf16 MFMA + bias + relu ----------
__global__ __launch_bounds__(128) void fusion_mfma(
    const __hip_bfloat16* __restrict__ fB, const __hip_bfloat16* __restrict__ fwB,
    const float* __restrict__ fb, float* __restrict__ out)
{
    __shared__ float lds_out[64 * 66];
    int t = threadIdx.x;
    int l = t & 63, wv = t >> 6;
    int lm = l & 15, quad = l >> 4;
    int pxbase = blockIdx.x * 64 + wv * 32;

    int px0 = pxbase + lm, px1 = pxbase + 16 + lm;
    int b = px0 / HW;
    int rem0 = px0 - b * HW, rem1 = px1 - b * HW;
    int y0 = rem0 / 96, x0 = rem0 - y0 * 96;
    int y1 = rem1 / 96, x1 = rem1 - y1 * 96;

    f32x4 acc[2][4] = {};
    const __hip_bfloat16* bp = fwB + lm * 2304 + quad * 8;

    #pragma unroll
    for (int ky = 0; ky < 3; ky++) {
        int yy0 = y0 + ky - 1, yy1 = y1 + ky - 1;
        #pragma unroll
        for (int kx = 0; kx < 3; kx++) {
            int xx0 = x0 + kx - 1, xx1 = x1 + kx - 1;
            bool ok0 = (yy0 >= 0) & (yy0 < 96) & (xx0 >= 0) & (xx0 < 96);
            bool ok1 = (yy1 >= 0) & (yy1 < 96) & (xx1 >= 0) & (xx1 < 96);
            const __hip_bfloat16* ap0 = fB + ((size_t)(b * HW + (ok0 ? (yy0 * 96 + xx0) : 0)) << 8) + quad * 8;
            const __hip_bfloat16* ap1 = fB + ((size_t)(b * HW + (ok1 ? (yy1 * 96 + xx1) : 0)) << 8) + quad * 8;
            int tap = (ky * 3 + kx) * 256;
            #pragma unroll 2
            for (int ci = 0; ci < 256; ci += 32) {
                short8 a0 = {}, a1 = {};
                if (ok0) a0 = *(const short8*)(ap0 + ci);
                if (ok1) a1 = *(const short8*)(ap1 + ci);
                short8 b0 = *(const short8*)(bp + tap + ci);
                short8 b1 = *(const short8*)(bp + 16 * 2304 + tap + ci);
                short8 b2 = *(const short8*)(bp + 32 * 2304 + tap + ci);
                short8 b3 = *(const short8*)(bp + 48 * 2304 + tap + ci);
                acc[0][0] = __builtin_amdgcn_mfma_f32_16x16x32_bf16(a0, b0, acc[0][0], 0, 0, 0);
                acc[0][1] = __builtin_amdgcn_mfma_f32_16x16x32_bf16(a0, b1, acc[0][1], 0, 0, 0);
                acc[0][2] = __builtin_amdgcn_mfma_f32_16x16x32_bf16(a0, b2, acc[0][2], 0, 0, 0);
                acc[0][3] = __builtin_amdgcn_mfma_f32_16x16x32_bf16(a0, b3, acc[0][3], 0, 0, 0);
                acc[1][0] = __builtin_amdgcn_mfma_f32_16x16x32_bf16(a1, b0, acc[1][0], 0, 0, 0);
                acc[1][1] = __builtin_amdgcn_mfma_f32_16x16x32_bf16(a1, b1, acc[1][1], 0, 0, 0);
                acc[1][2] = __builtin_amdgcn_mfma_f32_16x16x32_bf16(a1, b2, acc[1][2], 0, 0, 0);
                acc[1][3] = __builtin_amdgcn_mfma_f32_16x16x32_bf16(a1, b3, acc[1][3], 0, 0, 0);
            }
        }
    }

    #pragma unroll
    for (int mt = 0; mt < 2; mt++)
        #pragma unroll
        for (int nt = 0; nt < 4; nt++)
            #pragma unroll
            for (int r = 0; r < 4; r++) {
                int row = wv * 32 + mt * 16 + quad * 4 + r;
                int co = nt * 16 + lm;
                lds_out[co * 66 + row] = acc[mt][nt][r];
            }
    __syncthreads();

    int pxr = blockIdx.x * 64 + (t & 63);
    int br = pxr / HW; int remr = pxr - br * HW;
    #pragma unroll 4
    for (int i = 0; i < 32; i++) {
        int co = (t >> 6) * 32 + i;
        float v = lds_out[co * 66 + (t & 63)] + fb[co];
        out[(br * 64 + co) * HW + remr] = v > 0.f ? v : 0.f;
    }
}

extern "C" void kernel_launch(void* const* d_in, const int* in_sizes, int n_in,
                              void* d_out, int out_size, void* d_ws, size_t ws_size,
                              hipStream_t stream) {
    const float* sup = (const float*)d_in[0];
    const float* key = (const float*)d_in[1];
    const float* smw = (const float*)d_in[2];
    const float* smb = (const float*)d_in[3];
    const float* rw  = (const float*)d_in[4];
    const float* rb  = (const float*)d_in[5];
    const float *vw[3], *vb[3], *rpb[3];
    if (in_sizes[8] == 25) {
        for (int l = 0; l < 3; l++) {
            vw[l]  = (const float*)d_in[6 + 3 * l];
            vb[l]  = (const float*)d_in[7 + 3 * l];
            rpb[l] = (const float*)d_in[8 + 3 * l];
        }
    } else {
        for (int l = 0; l < 3; l++) {
            vw[l]  = (const float*)d_in[6 + 2 * l];
            vb[l]  = (const float*)d_in[7 + 2 * l];
            rpb[l] = (const float*)d_in[12 + l];
        }
    }
    const float* fw = (const float*)d_in[15];
    const float* fb = (const float*)d_in[16];
    float* out = (float*)d_out;

    float* wsf    = (float*)d_ws;
    float* smooth = wsf;                                    // 2359296 f
    float* sup2   = wsf + 2359296;                          // 2359296 f (NHWC)
    float* qT     = wsf + 4718592;                          // 2359296 f (NHWC)
    float* rwT    = wsf + 7077888;                          // 8192 f
    unsigned short* vwF = (unsigned short*)(wsf + 7086080); // 12288 bf16
    __hip_bfloat16* fusedB = (__hip_bfloat16*)(wsf + 7092224);  // 9437184 bf16
    __hip_bfloat16* fwB    = (__hip_bfloat16*)(wsf + 11810816); // 147456 bf16

    prep_weights<<<dim3(656), dim3(256), 0, stream>>>(rw, vw[0], vw[1], vw[2], fw, rwT, vwF, fwB);
    pack_kernel<<<dim3(3, 2, 384), dim3(32, 8), 0, stream>>>(key, sup, qT, fusedB);
    shift_smooth<<<dim3(576), dim3(256), 0, stream>>>(sup, smw, smb, smooth);
    reduce_kernel<<<dim3(576), dim3(256), 0, stream>>>(sup, smooth, rwT, rb, sup2);
    natten_fused<<<dim3(144, 4), dim3(256), 0, stream>>>(qT, sup2, vwF,
        vb[0], vb[1], vb[2], rpb[0], rpb[1], rpb[2], fusedB);
    fusion_mfma<<<dim3(576), dim3(128), 0, stream>>>(fusedB, fwB, fb, out);
}

// Round 6
// 252.491 us; speedup vs baseline: 2.5834x; 1.1717x over previous
//
#include <hip/hip_runtime.h>
#include <hip/hip_bf16.h>

#define HW 9216
#define NPX 36864

typedef __attribute__((ext_vector_type(8))) short short8;
typedef __attribute__((ext_vector_type(4))) float f32x4;

static __device__ __forceinline__ unsigned short f2bf(float x) {
    union { __hip_bfloat16 h; unsigned short u; } c; c.h = __float2bfloat16(x); return c.u;
}
static __device__ __forceinline__ float bfl(unsigned int u){ return __uint_as_float(u << 16); }
static __device__ __forceinline__ float bfh(unsigned int u){ return __uint_as_float(u & 0xffff0000u); }

// ---------- weight pre-transposes ----------
__global__ __launch_bounds__(256) void prep_weights(
    const float* __restrict__ rw, const float* __restrict__ vw0,
    const float* __restrict__ vw1, const float* __restrict__ vw2,
    const float* __restrict__ fw,
    float* __restrict__ rwT, unsigned short* __restrict__ vwF, unsigned short* __restrict__ fwF)
{
    int idx = blockIdx.x * 256 + threadIdx.x;
    if (idx < 8192) {                       // reduce_w (64,128) -> rwT[i][c]
        int c = idx & 63, i = idx >> 6;
        rwT[idx] = rw[c * 128 + i];
    } else if (idx < 20480) {               // v_w -> MFMA B-fragment order vwF[lvl][nt][kf][lane][j]
        int e = idx - 8192;
        int j = e & 7, lane = (e >> 3) & 63, kf = (e >> 9) & 1, nt = (e >> 10) & 3, lvl = e >> 12;
        int co = nt * 16 + (lane & 15);
        int k = kf * 32 + (lane >> 4) * 8 + j;
        const float* vw = (lvl == 0) ? vw0 : ((lvl == 1) ? vw1 : vw2);
        vwF[e] = f2bf(vw[co * 64 + k]);
    } else if (idx < 167936) {              // fusion_w (64,256,3,3) -> B-fragment order fwF[kc][nt][lane][j]
        int e = idx - 20480;
        int j = e & 7, lane = (e >> 3) & 63, nt = (e >> 9) & 3, kc = e >> 11;   // kc in 0..71
        int co = nt * 16 + (lane & 15);
        int k = kc * 32 + ((lane >> 4) << 3) + j;   // global K index: tap*256 + ci
        int tap = k >> 8, ci = k & 255;
        fwF[e] = f2bf(fw[co * 2304 + ci * 9 + tap]);
    }
}

// ---------- transpose key->qT (NHWC fp32) and sup->fused[ch 0:64] (bf16) ----------
__global__ void pack_kernel(const float* __restrict__ key, const float* __restrict__ sup,
                            float* __restrict__ qT, __hip_bfloat16* __restrict__ fused)
{
    __shared__ float lk[32][33], ls[32][33];
    int tx = threadIdx.x, ty = threadIdx.y;
    int x0 = blockIdx.x * 32, c0 = blockIdx.y * 32;
    int z = blockIdx.z; int b = z / 96, y = z - b * 96;
    #pragma unroll
    for (int i = 0; i < 32; i += 8) {
        int c = c0 + ty + i;
        lk[ty + i][tx] = key[((b * 64 + c) * 96 + y) * 96 + x0 + tx];
        ls[ty + i][tx] = sup[((b * 64 + c) * 96 + y) * 96 + x0 + tx];
    }
    __syncthreads();
    #pragma unroll
    for (int i = 0; i < 32; i += 8) {
        int px = (b * 96 + y) * 96 + x0 + ty + i;
        qT[px * 64 + c0 + tx]     = lk[tx][ty + i];
        fused[px * 256 + c0 + tx] = __hip_bfloat16(ls[tx][ty + i]);
    }
}

// ---------- shifted grouped 3x3 conv, LDS-staged, wave-uniform out-channel ----------
__global__ __launch_bounds__(256) void shift_smooth(const float* __restrict__ sup,
    const float* __restrict__ w, const float* __restrict__ bias, float* __restrict__ smooth)
{
    __shared__ __align__(16) float tile[8][34][36];
    int bid = blockIdx.x;                 // 576 = 4b * 8grp * 9sj * 2half
    int half = bid & 1;
    int sj   = (bid >> 1) % 9;
    int grp  = (bid / 18) & 7;
    int b    = bid / 144;
    int sby = sj / 3, sbx = sj % 3;
    int Y0 = sby * 32, X0 = sbx * 32;
    int sh = 3 * ((grp >= 5) - (grp < 3));
    int mm = (grp < 3) ? grp : ((grp < 5) ? ((grp == 3) ? 0 : 2) : (grp - 5));
    int sw = 3 * mm - 3;
    int t = threadIdx.x;

    const float* supg = sup + (size_t)(b * 64 + grp * 8) * HW;
    #pragma unroll
    for (int pp = 0; pp < 5; pp++) {
        int pos = pp * 256 + t;
        if (pos < 1156) {
            int r = pos / 34, u = pos - r * 34;
            int yy = Y0 - 1 + r, xx = X0 - 1 + u;
            int ys = yy - sh, xs = xx - sw;
            bool ok = (yy >= 0) & (yy < 96) & (xx >= 0) & (xx < 96) &
                      (ys >= 0) & (ys < 96) & (xs >= 0) & (xs < 96);
            int addr = ok ? (ys * 96 + xs) : 0;
            #pragma unroll
            for (int ic = 0; ic < 8; ic++) {
                float v = supg[(size_t)ic * HW + addr];
                tile[ic][r][u] = ok ? v : 0.f;
            }
        }
    }
    __syncthreads();

    int c = __builtin_amdgcn_readfirstlane(grp * 8 + half * 4 + (t >> 6));
    int lane = t & 63;
    int ty4 = lane >> 3, tx4 = lane & 7;
    int py0 = ty4 * 4, x0r = tx4 * 4;

    float bz = bias[c];
    float acc[4][4];
    #pragma unroll
    for (int jr = 0; jr < 4; jr++)
        #pragma unroll
        for (int j = 0; j < 4; j++) acc[jr][j] = bz;

    const float* wp = w + c * 72;
    for (int ic = 0; ic < 8; ic++) {
        float wr[9];
        #pragma unroll
        for (int q = 0; q < 9; q++) wr[q] = wp[ic * 9 + q];
        #pragma unroll
        for (int rr = 0; rr < 6; rr++) {
            float4 fa = *(const float4*)&tile[ic][py0 + rr][x0r];
            float4 fb4 = *(const float4*)&tile[ic][py0 + rr][x0r + 4];
            float f[6] = {fa.x, fa.y, fa.z, fa.w, fb4.x, fb4.y};
            #pragma unroll
            for (int ky = 0; ky < 3; ky++) {
                int jr = rr - ky;
                if (jr >= 0 && jr < 4) {
                    #pragma unroll
                    for (int j = 0; j < 4; j++)
                        acc[jr][j] += wr[ky*3]*f[j] + wr[ky*3+1]*f[j+1] + wr[ky*3+2]*f[j+2];
                }
            }
        }
    }

    float* op = smooth + ((size_t)(b * 64 + c) * 96 + Y0 + py0) * 96 + X0 + x0r;
    #pragma unroll
    for (int jr = 0; jr < 4; jr++) {
        float4 st = {acc[jr][0], acc[jr][1], acc[jr][2], acc[jr][3]};
        *(float4*)(op + (size_t)jr * 96) = st;
    }
}

// ---------- 1x1 reduce conv (128->64): px per lane, 16 co per thread ----------
__global__ __launch_bounds__(256) void reduce_kernel(const float* __restrict__ sup,
    const float* __restrict__ smooth, const float* __restrict__ rwT,
    const float* __restrict__ rb, float* __restrict__ sup2)
{
    int t = threadIdx.x;
    int lane = t & 63, wq = t >> 6;
    int px = blockIdx.x * 64 + lane;
    int b = px / HW; int rem = px - b * HW;
    const float* s1 = sup + (size_t)b * 64 * HW + rem;
    const float* s2 = smooth + (size_t)b * 64 * HW + rem;
    float acc[16];
    #pragma unroll
    for (int j = 0; j < 16; j++) acc[j] = rb[wq * 16 + j];
    for (int i = 0; i < 64; i++) {
        float v = s1[i * HW];
        #pragma unroll
        for (int j = 0; j < 16; j++) acc[j] += rwT[i * 64 + wq * 16 + j] * v;
    }
    for (int i = 0; i < 64; i++) {
        float v = s2[i * HW];
        #pragma unroll
        for (int j = 0; j < 16; j++) acc[j] += rwT[(64 + i) * 64 + wq * 16 + j] * v;
    }
    float* op = sup2 + (size_t)px * 64 + wq * 16;
    #pragma unroll
    for (int j = 0; j < 16; j += 4) { float4 st = {acc[j], acc[j+1], acc[j+2], acc[j+3]}; *(float4*)(op + j) = st; }
}

// ---------- fused 3-level neighborhood attention ----------
template<int KS>
__device__ __forceinline__ void level_softmax(int qc, int y, int x, int ni7, int nj7,
        const float* __restrict__ rpb, const float* dots_row, float* out_row)
{
    constexpr int R = KS / 2, KK = KS * KS, NB = 2 * KS - 1;
    constexpr int NE = (KK + 3) / 4;
    int ni = min(max(y - R, 0), 96 - KS), nj = min(max(x - R, 0), 96 - KS);
    int di = ni - ni7, dj = nj - nj7;
    int br = KS - 1 + ni - y, bc = KS - 1 + nj - x;
    float sv[NE];
    float mx = -1e30f;
    #pragma unroll
    for (int i = 0; i < NE; i++) {
        int e = qc + i * 4;
        if (e < KK) {
            int ey = e / KS, ex = e - ey * KS;
            float s = dots_row[(di + ey) * 7 + dj + ex] + rpb[(br + ey) * NB + bc + ex];
            sv[i] = s; mx = fmaxf(mx, s);
        } else sv[i] = -1e30f;
    }
    mx = fmaxf(mx, __shfl_xor(mx, 1)); mx = fmaxf(mx, __shfl_xor(mx, 2));
    float sum = 0.f;
    #pragma unroll
    for (int i = 0; i < NE; i++) { sv[i] = __expf(sv[i] - mx); sum += sv[i]; }
    sum += __shfl_xor(sum, 1); sum += __shfl_xor(sum, 2);
    float inv = 1.f / sum;
    #pragma unroll
    for (int i = 0; i < NE; i++) {
        int e = qc + i * 4;
        if (e < KK) out_row[e] = sv[i] * inv;
    }
}

__global__ __launch_bounds__(256) void natten_fused(
    const float* __restrict__ qT, const float* __restrict__ sup2,
    const unsigned short* __restrict__ vwF,
    const float* __restrict__ vb0, const float* __restrict__ vb1, const float* __restrict__ vb2,
    const float* __restrict__ rpb0, const float* __restrict__ rpb1, const float* __restrict__ rpb2,
    __hip_bfloat16* __restrict__ fused)
{
    __shared__ __align__(16) unsigned short khalo[196 * 72];
    __shared__ float dots[64][50];
    __shared__ float a3[64][12];
    __shared__ float a5[64][28];

    int t = threadIdx.x;
    int bb = blockIdx.y;
    int tx0 = (blockIdx.x % 12) * 8, ty0 = (blockIdx.x / 12) * 8;
    const float* kb = sup2 + (size_t)bb * HW * 64;

    for (int it = 0; it < 13; it++) {
        int qidx = it * 256 + t;
        if (qidx < 3136) {
            int cq = qidx & 15, pos = qidx >> 4;
            int py = pos / 14, pxx = pos - py * 14;
            int gy = min(max(ty0 - 3 + py, 0), 95);
            int gx = min(max(tx0 - 3 + pxx, 0), 95);
            float4 v = *(const float4*)(kb + (((size_t)gy * 96 + gx) << 6) + cq * 4);
            ushort4 pk = {f2bf(v.x), f2bf(v.y), f2bf(v.z), f2bf(v.w)};
            *(ushort4*)&khalo[pos * 72 + cq * 4] = pk;
        }
    }
    __syncthreads();

    int pxl = t >> 2, qc = t & 3;
    int pty = pxl >> 3, ptx = pxl & 7;
    int y = ty0 + pty, x = tx0 + ptx;
    int gpx = bb * HW + y * 96 + x;

    float qv[16];
    {
        const float* qp = qT + (size_t)gpx * 64 + qc * 16;
        #pragma unroll
        for (int j = 0; j < 16; j += 4) {
            float4 q4 = *(const float4*)(qp + j);
            qv[j] = q4.x; qv[j+1] = q4.y; qv[j+2] = q4.z; qv[j+3] = q4.w;
        }
    }

    int ni7 = min(max(y - 3, 0), 89), nj7 = min(max(x - 3, 0), 89);
    int ly = ni7 - (ty0 - 3), lx = nj7 - (tx0 - 3);

    for (int oy = 0; oy < 7; oy++) {
        #pragma unroll
        for (int ox = 0; ox < 7; ox++) {
            const unsigned short* kp = &khalo[((ly + oy) * 14 + lx + ox) * 72 + qc * 16];
            uint4 ka = *(const uint4*)kp;
            uint4 kc = *(const uint4*)(kp + 8);
            float d = qv[0]*bfl(ka.x) + qv[1]*bfh(ka.x) + qv[2]*bfl(ka.y) + qv[3]*bfh(ka.y)
                    + qv[4]*bfl(ka.z) + qv[5]*bfh(ka.z) + qv[6]*bfl(ka.w) + qv[7]*bfh(ka.w)
                    + qv[8]*bfl(kc.x) + qv[9]*bfh(kc.x) + qv[10]*bfl(kc.y) + qv[11]*bfh(kc.y)
                    + qv[12]*bfl(kc.z) + qv[13]*bfh(kc.z) + qv[14]*bfl(kc.w) + qv[15]*bfh(kc.w);
            d += __shfl_xor(d, 1);
            d += __shfl_xor(d, 2);
            if (qc == 0) dots[pxl][oy * 7 + ox] = d;
        }
    }

    level_softmax<3>(qc, y, x, ni7, nj7, rpb0, &dots[pxl][0], &a3[pxl][0]);
    level_softmax<5>(qc, y, x, ni7, nj7, rpb1, &dots[pxl][0], &a5[pxl][0]);
    level_softmax<7>(qc, y, x, ni7, nj7, rpb2, &dots[pxl][0], &dots[pxl][0]);

    int ni5 = min(max(y - 2, 0), 91), nj5 = min(max(x - 2, 0), 91);
    int ni3 = min(max(y - 1, 0), 93), nj3 = min(max(x - 1, 0), 93);
    int di5 = ni5 - ni7, dj5 = nj5 - nj7, di3 = ni3 - ni7, dj3 = nj3 - nj7;

    float s2[3][16];
    #pragma unroll
    for (int l = 0; l < 3; l++)
        #pragma unroll
        for (int j = 0; j < 16; j++) s2[l][j] = 0.f;

    for (int oy = 0; oy < 7; oy++) {
        #pragma unroll
        for (int ox = 0; ox < 7; ox++) {
            const unsigned short* kp = &khalo[((ly + oy) * 14 + lx + ox) * 72 + qc * 16];
            uint4 ka = *(const uint4*)kp;
            uint4 kc = *(const uint4*)(kp + 8);
            float kv[16] = {bfl(ka.x), bfh(ka.x), bfl(ka.y), bfh(ka.y),
                            bfl(ka.z), bfh(ka.z), bfl(ka.w), bfh(ka.w),
                            bfl(kc.x), bfh(kc.x), bfl(kc.y), bfh(kc.y),
                            bfl(kc.z), bfh(kc.z), bfl(kc.w), bfh(kc.w)};
            float w7 = dots[pxl][oy * 7 + ox];
            #pragma unroll
            for (int j = 0; j < 16; j++) s2[2][j] += w7 * kv[j];
            int e5y = oy - di5, e5x = ox - dj5;
            if ((unsigned)e5y < 5u && (unsigned)e5x < 5u) {
                float w5 = a5[pxl][e5y * 5 + e5x];
                #pragma unroll
                for (int j = 0; j < 16; j++) s2[1][j] += w5 * kv[j];
            }
            int e3y = oy - di3, e3x = ox - dj3;
            if ((unsigned)e3y < 3u && (unsigned)e3x < 3u) {
                float w3 = a3[pxl][e3y * 3 + e3x];
                #pragma unroll
                for (int j = 0; j < 16; j++) s2[0][j] += w3 * kv[j];
            }
        }
    }
    __syncthreads();

    unsigned short* sproj = khalo;
    #pragma unroll
    for (int l = 0; l < 3; l++) {
        unsigned int pk[8];
        #pragma unroll
        for (int j = 0; j < 8; j++)
            pk[j] = (unsigned int)f2bf(s2[l][2*j]) | ((unsigned int)f2bf(s2[l][2*j+1]) << 16);
        unsigned int* dst = (unsigned int*)&sproj[(l * 64 + pxl) * 72 + qc * 16];
        uint4 s0 = {pk[0], pk[1], pk[2], pk[3]};
        uint4 s1 = {pk[4], pk[5], pk[6], pk[7]};
        *(uint4*)dst = s0;
        *(uint4*)(dst + 4) = s1;
    }
    __syncthreads();

    int wv = t >> 6, lane = t & 63;
    int lm = lane & 15, quad = lane >> 4;
    #pragma unroll
    for (int l = 0; l < 3; l++) {
        f32x4 acc[4];
        #pragma unroll
        for (int nt = 0; nt < 4; nt++) acc[nt] = (f32x4){0.f, 0.f, 0.f, 0.f};
        #pragma unroll
        for (int kf = 0; kf < 2; kf++) {
            short8 a = *(const short8*)&sproj[(l * 64 + wv * 16 + lm) * 72 + kf * 32 + quad * 8];
            #pragma unroll
            for (int nt = 0; nt < 4; nt++) {
                short8 bfr = *(const short8*)&vwF[(((l * 4 + nt) * 2 + kf) * 64 + lane) * 8];
                acc[nt] = __builtin_amdgcn_mfma_f32_16x16x32_bf16(a, bfr, acc[nt], 0, 0, 0);
            }
        }
        const float* vbl = (l == 0) ? vb0 : ((l == 1) ? vb1 : vb2);
        #pragma unroll
        for (int nt = 0; nt < 4; nt++)
            #pragma unroll
            for (int r = 0; r < 4; r++) {
                int p = wv * 16 + quad * 4 + r;
                int co = nt * 16 + lm;
                int py = p >> 3, pxx = p & 7;
                size_t off = ((size_t)(bb * HW + (ty0 + py) * 96 + tx0 + pxx) << 8) + (l + 1) * 64 + co;
                fused[off] = __hip_bfloat16(acc[nt][r] + vbl[co]);
            }
    }
}

// ---------- 3x3 fusion conv (256->64): LDS-staged implicit-GEMM bf16 MFMA ----------
// block = 16x4 px tile x 64 co, 4 waves (wave = one 16-px row, all co).
// A-halo (18x6 px, one 64-ci chunk) staged in LDS, stride 72 ch (2-way banks = free).
// B in fragment order fwF[kc][nt][lane][j] -> coalesced 16B loads, L1-resident.
__global__ __launch_bounds__(256) void fusion_mfma(
    const __hip_bfloat16* __restrict__ fB, const unsigned short* __restrict__ fwF,
    const float* __restrict__ fb, float* __restrict__ out)
{
    __shared__ __align__(16) unsigned short ah[108 * 72];   // 18x6 halo, 64->72 ci pad: 15552 B
    __shared__ float lds_out[64 * 66];                       // 16896 B
    int t = threadIdx.x;
    int wv = t >> 6, lane = t & 63, lm = lane & 15, quad = lane >> 4;
    int X0 = blockIdx.x * 16, Y0 = blockIdx.y * 4, b = blockIdx.z;
    const unsigned short* fBu = (const unsigned short*)fB;

    f32x4 acc[4] = {};

    for (int chunk = 0; chunk < 4; chunk++) {
        __syncthreads();
        // stage halo: 108 px x 8 segs of 16B
        #pragma unroll
        for (int ee = 0; ee < 4; ee++) {
            int e = ee * 256 + t;
            if (e < 864) {
                int seg = e & 7, hp = e >> 3;
                int hy = hp / 18, hx = hp - hy * 18;
                int gy = Y0 - 1 + hy, gx = X0 - 1 + hx;
                bool ok = (gy >= 0) & (gy < 96) & (gx >= 0) & (gx < 96);
                short8 v = {};
                if (ok) v = *(const short8*)(fBu + (((size_t)(b * HW + gy * 96 + gx)) << 8) + chunk * 64 + seg * 8);
                *(short8*)&ah[hp * 72 + seg * 8] = v;
            }
        }
        __syncthreads();
        #pragma unroll
        for (int ky = 0; ky < 3; ky++) {
            #pragma unroll
            for (int kx = 0; kx < 3; kx++) {
                #pragma unroll
                for (int kf = 0; kf < 2; kf++) {
                    short8 a = *(const short8*)&ah[((wv + ky) * 18 + lm + kx) * 72 + kf * 32 + quad * 8];
                    int kc = (ky * 3 + kx) * 8 + chunk * 2 + kf;
                    const unsigned short* bp = fwF + ((size_t)(kc * 4) * 64 + lane) * 8;
                    acc[0] = __builtin_amdgcn_mfma_f32_16x16x32_bf16(a, *(const short8*)(bp),        acc[0], 0, 0, 0);
                    acc[1] = __builtin_amdgcn_mfma_f32_16x16x32_bf16(a, *(const short8*)(bp + 512),  acc[1], 0, 0, 0);
                    acc[2] = __builtin_amdgcn_mfma_f32_16x16x32_bf16(a, *(const short8*)(bp + 1024), acc[2], 0, 0, 0);
                    acc[3] = __builtin_amdgcn_mfma_f32_16x16x32_bf16(a, *(const short8*)(bp + 1536), acc[3], 0, 0, 0);
                }
            }
        }
    }

    // C/D: row(m)=quad*4+r = px within wave's row; col(n)=lm -> co within nt
    #pragma unroll
    for (int nt = 0; nt < 4; nt++)
        #pragma unroll
        for (int r = 0; r < 4; r++) {
            int p = wv * 16 + quad * 4 + r;
            int co = nt * 16 + lm;
            lds_out[co * 66 + p] = acc[nt][r];
        }
    __syncthreads();

    int p2 = t & 63, py = p2 >> 4, px2 = p2 & 15;
    float* ob = out + ((size_t)(b * 64) * 96 + Y0 + py) * 96 + X0 + px2;
    #pragma unroll 4
    for (int i = 0; i < 16; i++) {                 // 4 groups x 16 co = 64 co
        int co = (t >> 6) * 16 + i;
        float v = lds_out[co * 66 + p2] + fb[co];
        ob[(size_t)co * HW] = v > 0.f ? v : 0.f;
    }
}

extern "C" void kernel_launch(void* const* d_in, const int* in_sizes, int n_in,
                              void* d_out, int out_size, void* d_ws, size_t ws_size,
                              hipStream_t stream) {
    const float* sup = (const float*)d_in[0];
    const float* key = (const float*)d_in[1];
    const float* smw = (const float*)d_in[2];
    const float* smb = (const float*)d_in[3];
    const float* rw  = (const float*)d_in[4];
    const float* rb  = (const float*)d_in[5];
    const float *vw[3], *vb[3], *rpb[3];
    if (in_sizes[8] == 25) {
        for (int l = 0; l < 3; l++) {
            vw[l]  = (const float*)d_in[6 + 3 * l];
            vb[l]  = (const float*)d_in[7 + 3 * l];
            rpb[l] = (const float*)d_in[8 + 3 * l];
        }
    } else {
        for (int l = 0; l < 3; l++) {
            vw[l]  = (const float*)d_in[6 + 2 * l];
            vb[l]  = (const float*)d_in[7 + 2 * l];
            rpb[l] = (const float*)d_in[12 + l];
        }
    }
    const float* fw = (const float*)d_in[15];
    const float* fb = (const float*)d_in[16];
    float* out = (float*)d_out;

    float* wsf    = (float*)d_ws;
    float* smooth = wsf;                                    // 2359296 f
    float* sup2   = wsf + 2359296;                          // 2359296 f (NHWC)
    float* qT     = wsf + 4718592;                          // 2359296 f (NHWC)
    float* rwT    = wsf + 7077888;                          // 8192 f
    unsigned short* vwF = (unsigned short*)(wsf + 7086080); // 12288 bf16
    __hip_bfloat16* fusedB = (__hip_bfloat16*)(wsf + 7092224);  // 9437184 bf16
    unsigned short* fwF    = (unsigned short*)(wsf + 11810816); // 147456 bf16

    prep_weights<<<dim3(656), dim3(256), 0, stream>>>(rw, vw[0], vw[1], vw[2], fw, rwT, vwF, fwF);
    pack_kernel<<<dim3(3, 2, 384), dim3(32, 8), 0, stream>>>(key, sup, qT, fusedB);
    shift_smooth<<<dim3(576), dim3(256), 0, stream>>>(sup, smw, smb, smooth);
    reduce_kernel<<<dim3(576), dim3(256), 0, stream>>>(sup, smooth, rwT, rb, sup2);
    natten_fused<<<dim3(144, 4), dim3(256), 0, stream>>>(qT, sup2, vwF,
        vb[0], vb[1], vb[2], rpb[0], rpb[1], rpb[2], fusedB);
    fusion_mfma<<<dim3(6, 24, 4), dim3(256), 0, stream>>>(fusedB, fwF, fb, out);
}

// Round 7
// 224.709 us; speedup vs baseline: 2.9028x; 1.1236x over previous
//
#include <hip/hip_runtime.h>
#include <hip/hip_bf16.h>

#define HW 9216
#define NPX 36864

typedef __attribute__((ext_vector_type(8))) short short8;
typedef __attribute__((ext_vector_type(4))) float f32x4;

static __device__ __forceinline__ unsigned short f2bf(float x) {
    union { __hip_bfloat16 h; unsigned short u; } c; c.h = __float2bfloat16(x); return c.u;
}
static __device__ __forceinline__ float bfl(unsigned int u){ return __uint_as_float(u << 16); }
static __device__ __forceinline__ float bfh(unsigned int u){ return __uint_as_float(u & 0xffff0000u); }

// ---------- weight pre-transposes ----------
__global__ __launch_bounds__(256) void prep_weights(
    const float* __restrict__ rw, const float* __restrict__ vw0,
    const float* __restrict__ vw1, const float* __restrict__ vw2,
    const float* __restrict__ fw,
    float* __restrict__ rwT, unsigned short* __restrict__ vwF, unsigned short* __restrict__ fwF)
{
    int idx = blockIdx.x * 256 + threadIdx.x;
    if (idx < 8192) {                       // reduce_w (64,128) -> rwT[i][c]
        int c = idx & 63, i = idx >> 6;
        rwT[idx] = rw[c * 128 + i];
    } else if (idx < 20480) {               // v_w -> MFMA B-fragment order vwF[lvl][nt][kf][lane][j]
        int e = idx - 8192;
        int j = e & 7, lane = (e >> 3) & 63, kf = (e >> 9) & 1, nt = (e >> 10) & 3, lvl = e >> 12;
        int co = nt * 16 + (lane & 15);
        int k = kf * 32 + (lane >> 4) * 8 + j;
        const float* vw = (lvl == 0) ? vw0 : ((lvl == 1) ? vw1 : vw2);
        vwF[e] = f2bf(vw[co * 64 + k]);
    } else if (idx < 167936) {              // fusion_w (64,256,3,3) -> B-fragment order fwF[kc][nt][lane][j]
        int e = idx - 20480;
        int j = e & 7, lane = (e >> 3) & 63, nt = (e >> 9) & 3, kc = e >> 11;   // kc in 0..71
        int co = nt * 16 + (lane & 15);
        int k = kc * 32 + ((lane >> 4) << 3) + j;   // global K index: tap*256 + ci
        int tap = k >> 8, ci = k & 255;
        fwF[e] = f2bf(fw[co * 2304 + ci * 9 + tap]);
    }
}

// ---------- transpose key->qT (NHWC fp32) and sup->fused[ch 0:64] (bf16) ----------
__global__ void pack_kernel(const float* __restrict__ key, const float* __restrict__ sup,
                            float* __restrict__ qT, __hip_bfloat16* __restrict__ fused)
{
    __shared__ float lk[32][33], ls[32][33];
    int tx = threadIdx.x, ty = threadIdx.y;
    int x0 = blockIdx.x * 32, c0 = blockIdx.y * 32;
    int z = blockIdx.z; int b = z / 96, y = z - b * 96;
    #pragma unroll
    for (int i = 0; i < 32; i += 8) {
        int c = c0 + ty + i;
        lk[ty + i][tx] = key[((b * 64 + c) * 96 + y) * 96 + x0 + tx];
        ls[ty + i][tx] = sup[((b * 64 + c) * 96 + y) * 96 + x0 + tx];
    }
    __syncthreads();
    #pragma unroll
    for (int i = 0; i < 32; i += 8) {
        int px = (b * 96 + y) * 96 + x0 + ty + i;
        qT[px * 64 + c0 + tx]     = lk[tx][ty + i];
        fused[px * 256 + c0 + tx] = __hip_bfloat16(ls[tx][ty + i]);
    }
}

// ---------- shifted grouped 3x3 conv, LDS-staged, wave-uniform out-channel ----------
__global__ __launch_bounds__(256) void shift_smooth(const float* __restrict__ sup,
    const float* __restrict__ w, const float* __restrict__ bias, float* __restrict__ smooth)
{
    __shared__ __align__(16) float tile[8][34][36];
    int bid = blockIdx.x;                 // 576 = 4b * 8grp * 9sj * 2half
    int half = bid & 1;
    int sj   = (bid >> 1) % 9;
    int grp  = (bid / 18) & 7;
    int b    = bid / 144;
    int sby = sj / 3, sbx = sj % 3;
    int Y0 = sby * 32, X0 = sbx * 32;
    int sh = 3 * ((grp >= 5) - (grp < 3));
    int mm = (grp < 3) ? grp : ((grp < 5) ? ((grp == 3) ? 0 : 2) : (grp - 5));
    int sw = 3 * mm - 3;
    int t = threadIdx.x;

    const float* supg = sup + (size_t)(b * 64 + grp * 8) * HW;
    #pragma unroll
    for (int pp = 0; pp < 5; pp++) {
        int pos = pp * 256 + t;
        if (pos < 1156) {
            int r = pos / 34, u = pos - r * 34;
            int yy = Y0 - 1 + r, xx = X0 - 1 + u;
            int ys = yy - sh, xs = xx - sw;
            bool ok = (yy >= 0) & (yy < 96) & (xx >= 0) & (xx < 96) &
                      (ys >= 0) & (ys < 96) & (xs >= 0) & (xs < 96);
            int addr = ok ? (ys * 96 + xs) : 0;
            #pragma unroll
            for (int ic = 0; ic < 8; ic++) {
                float v = supg[(size_t)ic * HW + addr];
                tile[ic][r][u] = ok ? v : 0.f;
            }
        }
    }
    __syncthreads();

    int c = __builtin_amdgcn_readfirstlane(grp * 8 + half * 4 + (t >> 6));
    int lane = t & 63;
    int ty4 = lane >> 3, tx4 = lane & 7;
    int py0 = ty4 * 4, x0r = tx4 * 4;

    float bz = bias[c];
    float acc[4][4];
    #pragma unroll
    for (int jr = 0; jr < 4; jr++)
        #pragma unroll
        for (int j = 0; j < 4; j++) acc[jr][j] = bz;

    const float* wp = w + c * 72;
    for (int ic = 0; ic < 8; ic++) {
        float wr[9];
        #pragma unroll
        for (int q = 0; q < 9; q++) wr[q] = wp[ic * 9 + q];
        #pragma unroll
        for (int rr = 0; rr < 6; rr++) {
            float4 fa = *(const float4*)&tile[ic][py0 + rr][x0r];
            float4 fb4 = *(const float4*)&tile[ic][py0 + rr][x0r + 4];
            float f[6] = {fa.x, fa.y, fa.z, fa.w, fb4.x, fb4.y};
            #pragma unroll
            for (int ky = 0; ky < 3; ky++) {
                int jr = rr - ky;
                if (jr >= 0 && jr < 4) {
                    #pragma unroll
                    for (int j = 0; j < 4; j++)
                        acc[jr][j] += wr[ky*3]*f[j] + wr[ky*3+1]*f[j+1] + wr[ky*3+2]*f[j+2];
                }
            }
        }
    }

    float* op = smooth + ((size_t)(b * 64 + c) * 96 + Y0 + py0) * 96 + X0 + x0r;
    #pragma unroll
    for (int jr = 0; jr < 4; jr++) {
        float4 st = {acc[jr][0], acc[jr][1], acc[jr][2], acc[jr][3]};
        *(float4*)(op + (size_t)jr * 96) = st;
    }
}

// ---------- 1x1 reduce conv (128->64): weights in LDS (broadcast), px per lane ----------
__global__ __launch_bounds__(256) void reduce_kernel(const float* __restrict__ sup,
    const float* __restrict__ smooth, const float* __restrict__ rwT,
    const float* __restrict__ rb, float* __restrict__ sup2)
{
    __shared__ __align__(16) float wlds[8192];   // rwT[i][c], 32 KB
    int t = threadIdx.x;
    #pragma unroll
    for (int e = 0; e < 8; e++) {
        int idx = (e * 256 + t) * 4;
        *(float4*)&wlds[idx] = *(const float4*)&rwT[idx];
    }
    __syncthreads();

    int lane = t & 63, wq = t >> 6;
    int px = blockIdx.x * 64 + lane;
    int b = px / HW; int rem = px - b * HW;
    const float* s1 = sup + (size_t)b * 64 * HW + rem;
    const float* s2 = smooth + (size_t)b * 64 * HW + rem;
    float acc[16];
    #pragma unroll
    for (int j = 0; j < 16; j++) acc[j] = rb[wq * 16 + j];

    #pragma unroll 8
    for (int i = 0; i < 64; i++) {
        float v = s1[i * HW];
        const float* wr = &wlds[i * 64 + wq * 16];   // wave-uniform LDS addr -> broadcast
        float4 w0 = *(const float4*)wr, w1 = *(const float4*)(wr + 4);
        float4 w2 = *(const float4*)(wr + 8), w3 = *(const float4*)(wr + 12);
        acc[0] += w0.x * v;  acc[1] += w0.y * v;  acc[2] += w0.z * v;  acc[3] += w0.w * v;
        acc[4] += w1.x * v;  acc[5] += w1.y * v;  acc[6] += w1.z * v;  acc[7] += w1.w * v;
        acc[8] += w2.x * v;  acc[9] += w2.y * v;  acc[10] += w2.z * v; acc[11] += w2.w * v;
        acc[12] += w3.x * v; acc[13] += w3.y * v; acc[14] += w3.z * v; acc[15] += w3.w * v;
    }
    #pragma unroll 8
    for (int i = 0; i < 64; i++) {
        float v = s2[i * HW];
        const float* wr = &wlds[(64 + i) * 64 + wq * 16];
        float4 w0 = *(const float4*)wr, w1 = *(const float4*)(wr + 4);
        float4 w2 = *(const float4*)(wr + 8), w3 = *(const float4*)(wr + 12);
        acc[0] += w0.x * v;  acc[1] += w0.y * v;  acc[2] += w0.z * v;  acc[3] += w0.w * v;
        acc[4] += w1.x * v;  acc[5] += w1.y * v;  acc[6] += w1.z * v;  acc[7] += w1.w * v;
        acc[8] += w2.x * v;  acc[9] += w2.y * v;  acc[10] += w2.z * v; acc[11] += w2.w * v;
        acc[12] += w3.x * v; acc[13] += w3.y * v; acc[14] += w3.z * v; acc[15] += w3.w * v;
    }

    float* op = sup2 + (size_t)px * 64 + wq * 16;
    #pragma unroll
    for (int j = 0; j < 16; j += 4) { float4 st = {acc[j], acc[j+1], acc[j+2], acc[j+3]}; *(float4*)(op + j) = st; }
}

// ---------- fused 3-level neighborhood attention ----------
template<int KS>
__device__ __forceinline__ void level_softmax(int qc, int y, int x, int ni7, int nj7,
        const float* __restrict__ rpb, const float* dots_row, float* out_row)
{
    constexpr int R = KS / 2, KK = KS * KS, NB = 2 * KS - 1;
    constexpr int NE = (KK + 3) / 4;
    int ni = min(max(y - R, 0), 96 - KS), nj = min(max(x - R, 0), 96 - KS);
    int di = ni - ni7, dj = nj - nj7;
    int br = KS - 1 + ni - y, bc = KS - 1 + nj - x;
    float sv[NE];
    float mx = -1e30f;
    #pragma unroll
    for (int i = 0; i < NE; i++) {
        int e = qc + i * 4;
        if (e < KK) {
            int ey = e / KS, ex = e - ey * KS;
            float s = dots_row[(di + ey) * 7 + dj + ex] + rpb[(br + ey) * NB + bc + ex];
            sv[i] = s; mx = fmaxf(mx, s);
        } else sv[i] = -1e30f;
    }
    mx = fmaxf(mx, __shfl_xor(mx, 1)); mx = fmaxf(mx, __shfl_xor(mx, 2));
    float sum = 0.f;
    #pragma unroll
    for (int i = 0; i < NE; i++) { sv[i] = __expf(sv[i] - mx); sum += sv[i]; }
    sum += __shfl_xor(sum, 1); sum += __shfl_xor(sum, 2);
    float inv = 1.f / sum;
    #pragma unroll
    for (int i = 0; i < NE; i++) {
        int e = qc + i * 4;
        if (e < KK) out_row[e] = sv[i] * inv;
    }
}

__global__ __launch_bounds__(256) void natten_fused(
    const float* __restrict__ qT, const float* __restrict__ sup2,
    const unsigned short* __restrict__ vwF,
    const float* __restrict__ vb0, const float* __restrict__ vb1, const float* __restrict__ vb2,
    const float* __restrict__ rpb0, const float* __restrict__ rpb1, const float* __restrict__ rpb2,
    __hip_bfloat16* __restrict__ fused)
{
    __shared__ __align__(16) unsigned short khalo[196 * 72];
    __shared__ float dots[64][50];
    __shared__ float a3[64][12];
    __shared__ float a5[64][28];

    int t = threadIdx.x;
    int bb = blockIdx.y;
    int tx0 = (blockIdx.x % 12) * 8, ty0 = (blockIdx.x / 12) * 8;
    const float* kb = sup2 + (size_t)bb * HW * 64;

    for (int it = 0; it < 13; it++) {
        int qidx = it * 256 + t;
        if (qidx < 3136) {
            int cq = qidx & 15, pos = qidx >> 4;
            int py = pos / 14, pxx = pos - py * 14;
            int gy = min(max(ty0 - 3 + py, 0), 95);
            int gx = min(max(tx0 - 3 + pxx, 0), 95);
            float4 v = *(const float4*)(kb + (((size_t)gy * 96 + gx) << 6) + cq * 4);
            ushort4 pk = {f2bf(v.x), f2bf(v.y), f2bf(v.z), f2bf(v.w)};
            *(ushort4*)&khalo[pos * 72 + cq * 4] = pk;
        }
    }
    __syncthreads();

    int pxl = t >> 2, qc = t & 3;
    int pty = pxl >> 3, ptx = pxl & 7;
    int y = ty0 + pty, x = tx0 + ptx;
    int gpx = bb * HW + y * 96 + x;

    float qv[16];
    {
        const float* qp = qT + (size_t)gpx * 64 + qc * 16;
        #pragma unroll
        for (int j = 0; j < 16; j += 4) {
            float4 q4 = *(const float4*)(qp + j);
            qv[j] = q4.x; qv[j+1] = q4.y; qv[j+2] = q4.z; qv[j+3] = q4.w;
        }
    }

    int ni7 = min(max(y - 3, 0), 89), nj7 = min(max(x - 3, 0), 89);
    int ly = ni7 - (ty0 - 3), lx = nj7 - (tx0 - 3);

    for (int oy = 0; oy < 7; oy++) {
        #pragma unroll
        for (int ox = 0; ox < 7; ox++) {
            const unsigned short* kp = &khalo[((ly + oy) * 14 + lx + ox) * 72 + qc * 16];
            uint4 ka = *(const uint4*)kp;
            uint4 kc = *(const uint4*)(kp + 8);
            float d = qv[0]*bfl(ka.x) + qv[1]*bfh(ka.x) + qv[2]*bfl(ka.y) + qv[3]*bfh(ka.y)
                    + qv[4]*bfl(ka.z) + qv[5]*bfh(ka.z) + qv[6]*bfl(ka.w) + qv[7]*bfh(ka.w)
                    + qv[8]*bfl(kc.x) + qv[9]*bfh(kc.x) + qv[10]*bfl(kc.y) + qv[11]*bfh(kc.y)
                    + qv[12]*bfl(kc.z) + qv[13]*bfh(kc.z) + qv[14]*bfl(kc.w) + qv[15]*bfh(kc.w);
            d += __shfl_xor(d, 1);
            d += __shfl_xor(d, 2);
            if (qc == 0) dots[pxl][oy * 7 + ox] = d;
        }
    }

    level_softmax<3>(qc, y, x, ni7, nj7, rpb0, &dots[pxl][0], &a3[pxl][0]);
    level_softmax<5>(qc, y, x, ni7, nj7, rpb1, &dots[pxl][0], &a5[pxl][0]);
    level_softmax<7>(qc, y, x, ni7, nj7, rpb2, &dots[pxl][0], &dots[pxl][0]);

    int ni5 = min(max(y - 2, 0), 91), nj5 = min(max(x - 2, 0), 91);
    int ni3 = min(max(y - 1, 0), 93), nj3 = min(max(x - 1, 0), 93);
    int di5 = ni5 - ni7, dj5 = nj5 - nj7, di3 = ni3 - ni7, dj3 = nj3 - nj7;

    float s2[3][16];
    #pragma unroll
    for (int l = 0; l < 3; l++)
        #pragma unroll
        for (int j = 0; j < 16; j++) s2[l][j] = 0.f;

    for (int oy = 0; oy < 7; oy++) {
        #pragma unroll
        for (int ox = 0; ox < 7; ox++) {
            const unsigned short* kp = &khalo[((ly + oy) * 14 + lx + ox) * 72 + qc * 16];
            uint4 ka = *(const uint4*)kp;
            uint4 kc = *(const uint4*)(kp + 8);
            float kv[16] = {bfl(ka.x), bfh(ka.x), bfl(ka.y), bfh(ka.y),
                            bfl(ka.z), bfh(ka.z), bfl(ka.w), bfh(ka.w),
                            bfl(kc.x), bfh(kc.x), bfl(kc.y), bfh(kc.y),
                            bfl(kc.z), bfh(kc.z), bfl(kc.w), bfh(kc.w)};
            float w7 = dots[pxl][oy * 7 + ox];
            #pragma unroll
            for (int j = 0; j < 16; j++) s2[2][j] += w7 * kv[j];
            int e5y = oy - di5, e5x = ox - dj5;
            if ((unsigned)e5y < 5u && (unsigned)e5x < 5u) {
                float w5 = a5[pxl][e5y * 5 + e5x];
                #pragma unroll
                for (int j = 0; j < 16; j++) s2[1][j] += w5 * kv[j];
            }
            int e3y = oy - di3, e3x = ox - dj3;
            if ((unsigned)e3y < 3u && (unsigned)e3x < 3u) {
                float w3 = a3[pxl][e3y * 3 + e3x];
                #pragma unroll
                for (int j = 0; j < 16; j++) s2[0][j] += w3 * kv[j];
            }
        }
    }
    __syncthreads();

    unsigned short* sproj = khalo;
    #pragma unroll
    for (int l = 0; l < 3; l++) {
        unsigned int pk[8];
        #pragma unroll
        for (int j = 0; j < 8; j++)
            pk[j] = (unsigned int)f2bf(s2[l][2*j]) | ((unsigned int)f2bf(s2[l][2*j+1]) << 16);
        unsigned int* dst = (unsigned int*)&sproj[(l * 64 + pxl) * 72 + qc * 16];
        uint4 s0 = {pk[0], pk[1], pk[2], pk[3]};
        uint4 s1 = {pk[4], pk[5], pk[6], pk[7]};
        *(uint4*)dst = s0;
        *(uint4*)(dst + 4) = s1;
    }
    __syncthreads();

    int wv = t >> 6, lane = t & 63;
    int lm = lane & 15, quad = lane >> 4;
    #pragma unroll
    for (int l = 0; l < 3; l++) {
        f32x4 acc[4];
        #pragma unroll
        for (int nt = 0; nt < 4; nt++) acc[nt] = (f32x4){0.f, 0.f, 0.f, 0.f};
        #pragma unroll
        for (int kf = 0; kf < 2; kf++) {
            short8 a = *(const short8*)&sproj[(l * 64 + wv * 16 + lm) * 72 + kf * 32 + quad * 8];
            #pragma unroll
            for (int nt = 0; nt < 4; nt++) {
                short8 bfr = *(const short8*)&vwF[(((l * 4 + nt) * 2 + kf) * 64 + lane) * 8];
                acc[nt] = __builtin_amdgcn_mfma_f32_16x16x32_bf16(a, bfr, acc[nt], 0, 0, 0);
            }
        }
        const float* vbl = (l == 0) ? vb0 : ((l == 1) ? vb1 : vb2);
        #pragma unroll
        for (int nt = 0; nt < 4; nt++)
            #pragma unroll
            for (int r = 0; r < 4; r++) {
                int p = wv * 16 + quad * 4 + r;
                int co = nt * 16 + lm;
                int py = p >> 3, pxx = p & 7;
                size_t off = ((size_t)(bb * HW + (ty0 + py) * 96 + tx0 + pxx) << 8) + (l + 1) * 64 + co;
                fused[off] = __hip_bfloat16(acc[nt][r] + vbl[co]);
            }
    }
}

// ---------- 3x3 fusion conv (256->64): LDS-staged implicit-GEMM bf16 MFMA ----------
__global__ __launch_bounds__(256) void fusion_mfma(
    const __hip_bfloat16* __restrict__ fB, const unsigned short* __restrict__ fwF,
    const float* __restrict__ fb, float* __restrict__ out)
{
    __shared__ __align__(16) unsigned short ah[108 * 72];   // 18x6 halo, 64->72 ci pad: 15552 B
    __shared__ float lds_out[64 * 66];                       // 16896 B
    int t = threadIdx.x;
    int wv = t >> 6, lane = t & 63, lm = lane & 15, quad = lane >> 4;
    int X0 = blockIdx.x * 16, Y0 = blockIdx.y * 4, b = blockIdx.z;
    const unsigned short* fBu = (const unsigned short*)fB;

    f32x4 acc[4] = {};

    for (int chunk = 0; chunk < 4; chunk++) {
        __syncthreads();
        #pragma unroll
        for (int ee = 0; ee < 4; ee++) {
            int e = ee * 256 + t;
            if (e < 864) {
                int seg = e & 7, hp = e >> 3;
                int hy = hp / 18, hx = hp - hy * 18;
                int gy = Y0 - 1 + hy, gx = X0 - 1 + hx;
                bool ok = (gy >= 0) & (gy < 96) & (gx >= 0) & (gx < 96);
                short8 v = {};
                if (ok) v = *(const short8*)(fBu + (((size_t)(b * HW + gy * 96 + gx)) << 8) + chunk * 64 + seg * 8);
                *(short8*)&ah[hp * 72 + seg * 8] = v;
            }
        }
        __syncthreads();
        #pragma unroll
        for (int ky = 0; ky < 3; ky++) {
            #pragma unroll
            for (int kx = 0; kx < 3; kx++) {
                #pragma unroll
                for (int kf = 0; kf < 2; kf++) {
                    short8 a = *(const short8*)&ah[((wv + ky) * 18 + lm + kx) * 72 + kf * 32 + quad * 8];
                    int kc = (ky * 3 + kx) * 8 + chunk * 2 + kf;
                    const unsigned short* bp = fwF + ((size_t)(kc * 4) * 64 + lane) * 8;
                    acc[0] = __builtin_amdgcn_mfma_f32_16x16x32_bf16(a, *(const short8*)(bp),        acc[0], 0, 0, 0);
                    acc[1] = __builtin_amdgcn_mfma_f32_16x16x32_bf16(a, *(const short8*)(bp + 512),  acc[1], 0, 0, 0);
                    acc[2] = __builtin_amdgcn_mfma_f32_16x16x32_bf16(a, *(const short8*)(bp + 1024), acc[2], 0, 0, 0);
                    acc[3] = __builtin_amdgcn_mfma_f32_16x16x32_bf16(a, *(const short8*)(bp + 1536), acc[3], 0, 0, 0);
                }
            }
        }
    }

    #pragma unroll
    for (int nt = 0; nt < 4; nt++)
        #pragma unroll
        for (int r = 0; r < 4; r++) {
            int p = wv * 16 + quad * 4 + r;
            int co = nt * 16 + lm;
            lds_out[co * 66 + p] = acc[nt][r];
        }
    __syncthreads();

    int p2 = t & 63, py = p2 >> 4, px2 = p2 & 15;
    float* ob = out + ((size_t)(b * 64) * 96 + Y0 + py) * 96 + X0 + px2;
    #pragma unroll 4
    for (int i = 0; i < 16; i++) {
        int co = (t >> 6) * 16 + i;
        float v = lds_out[co * 66 + p2] + fb[co];
        ob[(size_t)co * HW] = v > 0.f ? v : 0.f;
    }
}

extern "C" void kernel_launch(void* const* d_in, const int* in_sizes, int n_in,
                              void* d_out, int out_size, void* d_ws, size_t ws_size,
                              hipStream_t stream) {
    const float* sup = (const float*)d_in[0];
    const float* key = (const float*)d_in[1];
    const float* smw = (const float*)d_in[2];
    const float* smb = (const float*)d_in[3];
    const float* rw  = (const float*)d_in[4];
    const float* rb  = (const float*)d_in[5];
    const float *vw[3], *vb[3], *rpb[3];
    if (in_sizes[8] == 25) {
        for (int l = 0; l < 3; l++) {
            vw[l]  = (const float*)d_in[6 + 3 * l];
            vb[l]  = (const float*)d_in[7 + 3 * l];
            rpb[l] = (const float*)d_in[8 + 3 * l];
        }
    } else {
        for (int l = 0; l < 3; l++) {
            vw[l]  = (const float*)d_in[6 + 2 * l];
            vb[l]  = (const float*)d_in[7 + 2 * l];
            rpb[l] = (const float*)d_in[12 + l];
        }
    }
    const float* fw = (const float*)d_in[15];
    const float* fb = (const float*)d_in[16];
    float* out = (float*)d_out;

    float* wsf    = (float*)d_ws;
    float* smooth = wsf;                                    // 2359296 f
    float* sup2   = wsf + 2359296;                          // 2359296 f (NHWC)
    float* qT     = wsf + 4718592;                          // 2359296 f (NHWC)
    float* rwT    = wsf + 7077888;                          // 8192 f
    unsigned short* vwF = (unsigned short*)(wsf + 7086080); // 12288 bf16
    __hip_bfloat16* fusedB = (__hip_bfloat16*)(wsf + 7092224);  // 9437184 bf16
    unsigned short* fwF    = (unsigned short*)(wsf + 11810816); // 147456 bf16

    prep_weights<<<dim3(656), dim3(256), 0, stream>>>(rw, vw[0], vw[1], vw[2], fw, rwT, vwF, fwF);
    pack_kernel<<<dim3(3, 2, 384), dim3(32, 8), 0, stream>>>(key, sup, qT, fusedB);
    shift_smooth<<<dim3(576), dim3(256), 0, stream>>>(sup, smw, smb, smooth);
    reduce_kernel<<<dim3(576), dim3(256), 0, stream>>>(sup, smooth, rwT, rb, sup2);
    natten_fused<<<dim3(144, 4), dim3(256), 0, stream>>>(qT, sup2, vwF,
        vb[0], vb[1], vb[2], rpb[0], rpb[1], rpb[2], fusedB);
    fusion_mfma<<<dim3(6, 24, 4), dim3(256), 0, stream>>>(fusedB, fwF, fb, out);
}